// Round 3
// baseline (1662.817 us; speedup 1.0000x reference)
//
#include <hip/hip_runtime.h>

#define N_NODES 50000
#define DIM 128
#define N_LAYERS 5
#define BN_EPS 1e-5f

typedef __attribute__((ext_vector_type(8))) short short8;
typedef __attribute__((ext_vector_type(4))) float f32x4;

__device__ __forceinline__ float bf2f(unsigned int u16) {
    union { unsigned int i; float f; } c; c.i = u16 << 16; return c.f;
}
__device__ __forceinline__ unsigned short f2bf(float f) {
    union { float f; unsigned int i; } c; c.f = f;
    unsigned int v = c.i + 0x7FFFu + ((c.i >> 16) & 1u);   // RNE
    return (unsigned short)(v >> 16);
}

// ---------------- CSR build ----------------

__global__ void hist_kernel(const int* __restrict__ dst, int n_edges, int* __restrict__ counts) {
    int e = blockIdx.x * 256 + threadIdx.x;
    if (e < n_edges) atomicAdd(&counts[dst[e]], 1);
}

__global__ void scan_local(const int* __restrict__ counts, int n,
                           int* __restrict__ offsets, int* __restrict__ blocksums) {
    __shared__ int temp[256];
    int t = threadIdx.x;
    int i = blockIdx.x * 256 + t;
    int v = (i < n) ? counts[i] : 0;
    temp[t] = v;
    __syncthreads();
    for (int off = 1; off < 256; off <<= 1) {
        int add = (t >= off) ? temp[t - off] : 0;
        __syncthreads();
        temp[t] += add;
        __syncthreads();
    }
    if (i < n) offsets[i] = temp[t] - v;
    if (t == 255) blocksums[blockIdx.x] = temp[255];
}

__global__ void scan_block(int* __restrict__ blocksums, int nb) {
    __shared__ int temp[256];
    int t = threadIdx.x;
    int v = (t < nb) ? blocksums[t] : 0;
    temp[t] = v;
    __syncthreads();
    for (int off = 1; off < 256; off <<= 1) {
        int add = (t >= off) ? temp[t - off] : 0;
        __syncthreads();
        temp[t] += add;
        __syncthreads();
    }
    if (t < nb) blocksums[t] = temp[t] - v;
}

__global__ void scan_add(int* __restrict__ offsets, int* __restrict__ cursor,
                         const int* __restrict__ blocksums, int n, int n_edges) {
    int i = blockIdx.x * 256 + threadIdx.x;
    if (i < n) {
        int val = offsets[i] + blocksums[blockIdx.x];
        offsets[i] = val;
        cursor[i] = val;
    }
    if (i == 0) offsets[n] = n_edges;
}

__global__ void scatter_kernel(const int* __restrict__ src, const int* __restrict__ dst,
                               int n_edges, int* __restrict__ cursor, int* __restrict__ csr_src) {
    int e = blockIdx.x * 256 + threadIdx.x;
    if (e < n_edges) {
        int p = atomicAdd(&cursor[dst[e]], 1);
        csr_src[p] = src[e];
    }
}

// ---------------- prep ----------------

// pack W1/W2 (all layers) into MFMA B-fragment order, hi+lo bf16 planes.
// per [lay][mat]: hi plane 16384 shorts, then lo plane 16384 shorts.
// fragment layout within plane: [ks][nt][lane][j]; for mat==1 (W2) rows
// k-permuted (kp -> orig k = (kp&7)*16 + (kp>>3)) to match LDS mid packing.
__global__ void wpack_prep(const float* __restrict__ W1, const float* __restrict__ W2,
                           unsigned short* __restrict__ wp) {
    int idx = blockIdx.x * 256 + threadIdx.x;
    if (idx >= N_LAYERS * 2 * 16384) return;
    int j    = idx & 7;
    int lane = (idx >> 3) & 63;
    int nt   = (idx >> 9) & 7;
    int ks   = (idx >> 12) & 3;
    int mat  = (idx >> 14) & 1;
    int lay  = idx >> 15;
    int l15 = lane & 15, l4 = lane >> 4;
    int col = nt * 16 + l15;
    int kp = ks * 32 + l4 * 8 + j;
    int k = mat ? ((kp & 7) * 16 + (kp >> 3)) : kp;
    const float* W = mat ? W2 : W1;
    float w = W[((size_t)lay * 128 + k) * 128 + col];
    unsigned short hi = f2bf(w);
    unsigned short lo = f2bf(w - bf2f(hi));
    size_t base = (size_t)(lay * 2 + mat) * 32768;
    size_t inner = (size_t)((ks * 8 + nt) * 64 + lane) * 8 + j;
    wp[base + inner] = hi;
    wp[base + 16384 + inner] = lo;
}

// ---------------- per-layer kernels ----------------

// one wave per node, fp32 accumulate; emit hi/lo bf16 planes for the MFMA MLP
__global__ void agg_kernel(const float* __restrict__ x, const int* __restrict__ csr_src,
                           const int* __restrict__ offsets,
                           unsigned int* __restrict__ h_hi_u, unsigned int* __restrict__ h_lo_u) {
    int wave = threadIdx.x >> 6;
    int lane = threadIdx.x & 63;
    int node = blockIdx.x * 4 + wave;
    if (node >= N_NODES) return;
    int beg = offsets[node], end = offsets[node + 1];
    float2 acc = ((const float2*)(x + (size_t)node * DIM))[lane];   // h = x + agg
    for (int e = beg; e < end; ++e) {
        int s = csr_src[e];
        float2 v = ((const float2*)(x + (size_t)s * DIM))[lane];
        acc.x += v.x;
        acc.y += v.y;
    }
    unsigned short hx = f2bf(acc.x), hy = f2bf(acc.y);
    unsigned short lx = f2bf(acc.x - bf2f(hx)), ly = f2bf(acc.y - bf2f(hy));
    h_hi_u[node * 64 + lane] = (unsigned int)hx | ((unsigned int)hy << 16);
    h_lo_u[node * 64 + lane] = (unsigned int)lx | ((unsigned int)ly << 16);
}

// fused MFMA MLP (bf16x2 split, 3-product): ReLU(h@W1+b1)@W2+b2 -> ReLU
// -> h_raw (fp32) + per-block BN partials
__global__ __launch_bounds__(128) void mlp_mfma(
        const unsigned short* __restrict__ h_hi, const unsigned short* __restrict__ h_lo,
        const short8* __restrict__ wp1, const float* __restrict__ b1,
        const short8* __restrict__ wp2, const float* __restrict__ b2,
        float* __restrict__ h_raw,
        float* __restrict__ part_s, float* __restrict__ part_q) {
    __shared__ unsigned short mid_hi[2][2][16][128];   // [wave][m][row][kp], XOR-swizzled
    __shared__ unsigned short mid_lo[2][2][16][128];
    __shared__ float red_s[2][128], red_q[2][128];
    int t = threadIdx.x, wave = t >> 6, l = t & 63;
    int l15 = l & 15, l4 = l >> 4;
    int row_base = blockIdx.x * 64 + wave * 32;

    int r0 = row_base + l15, r1 = r0 + 16;
    int cr0 = min(r0, N_NODES - 1), cr1 = min(r1, N_NODES - 1);
    const short8* ah0p = (const short8*)(h_hi + (size_t)cr0 * 128);
    const short8* ah1p = (const short8*)(h_hi + (size_t)cr1 * 128);
    const short8* al0p = (const short8*)(h_lo + (size_t)cr0 * 128);
    const short8* al1p = (const short8*)(h_lo + (size_t)cr1 * 128);

    const short8* wp1l = wp1 + 2048;   // lo plane (16384 shorts)
    const short8* wp2l = wp2 + 2048;

    f32x4 acc[2][8];
#pragma unroll
    for (int m = 0; m < 2; ++m)
#pragma unroll
        for (int nt = 0; nt < 8; ++nt) acc[m][nt] = (f32x4)0.0f;

#pragma unroll
    for (int ks = 0; ks < 4; ++ks) {
        short8 ah0 = ah0p[ks * 4 + l4];   // A[row=l&15][k = ks*32 + (l>>4)*8 + j]
        short8 ah1 = ah1p[ks * 4 + l4];
        short8 al0 = al0p[ks * 4 + l4];
        short8 al1 = al1p[ks * 4 + l4];
#pragma unroll
        for (int nt = 0; nt < 8; ++nt) {
            short8 whi = wp1[(ks * 8 + nt) * 64 + l];
            short8 wlo = wp1l[(ks * 8 + nt) * 64 + l];
            acc[0][nt] = __builtin_amdgcn_mfma_f32_16x16x32_bf16(ah0, whi, acc[0][nt], 0, 0, 0);
            acc[0][nt] = __builtin_amdgcn_mfma_f32_16x16x32_bf16(al0, whi, acc[0][nt], 0, 0, 0);
            acc[0][nt] = __builtin_amdgcn_mfma_f32_16x16x32_bf16(ah0, wlo, acc[0][nt], 0, 0, 0);
            acc[1][nt] = __builtin_amdgcn_mfma_f32_16x16x32_bf16(ah1, whi, acc[1][nt], 0, 0, 0);
            acc[1][nt] = __builtin_amdgcn_mfma_f32_16x16x32_bf16(al1, whi, acc[1][nt], 0, 0, 0);
            acc[1][nt] = __builtin_amdgcn_mfma_f32_16x16x32_bf16(ah1, wlo, acc[1][nt], 0, 0, 0);
        }
    }

    float b1v[8];
#pragma unroll
    for (int nt = 0; nt < 8; ++nt) b1v[nt] = b1[nt * 16 + l15];

    // bias + ReLU + hi/lo split; pack lane's 8 cols (kp = l15*8 + nt) -> LDS
#pragma unroll
    for (int m = 0; m < 2; ++m) {
#pragma unroll
        for (int rr = 0; rr < 4; ++rr) {
            int row = l4 * 4 + rr;   // C/D: row=(l>>4)*4+reg, col=nt*16+l15
            short8 ph, pl;
#pragma unroll
            for (int nt = 0; nt < 8; ++nt) {
                float v = fmaxf(acc[m][nt][rr] + b1v[nt], 0.0f);
                unsigned short hv = f2bf(v);
                ph[nt] = (short)hv;
                pl[nt] = (short)f2bf(v - bf2f(hv));
            }
            int off = (l15 * 16) ^ ((row & 7) << 4);
            *(short8*)((char*)&mid_hi[wave][m][row][0] + off) = ph;
            *(short8*)((char*)&mid_lo[wave][m][row][0] + off) = pl;
        }
    }
    __syncthreads();

    f32x4 acc2[2][8];
#pragma unroll
    for (int m = 0; m < 2; ++m)
#pragma unroll
        for (int nt = 0; nt < 8; ++nt) acc2[m][nt] = (f32x4)0.0f;

#pragma unroll
    for (int ks = 0; ks < 4; ++ks) {
        int off = (ks * 64 + l4 * 16) ^ ((l15 & 7) << 4);
        short8 ah0 = *(const short8*)((char*)&mid_hi[wave][0][l15][0] + off);
        short8 ah1 = *(const short8*)((char*)&mid_hi[wave][1][l15][0] + off);
        short8 al0 = *(const short8*)((char*)&mid_lo[wave][0][l15][0] + off);
        short8 al1 = *(const short8*)((char*)&mid_lo[wave][1][l15][0] + off);
#pragma unroll
        for (int nt = 0; nt < 8; ++nt) {
            short8 whi = wp2[(ks * 8 + nt) * 64 + l];
            short8 wlo = wp2l[(ks * 8 + nt) * 64 + l];
            acc2[0][nt] = __builtin_amdgcn_mfma_f32_16x16x32_bf16(ah0, whi, acc2[0][nt], 0, 0, 0);
            acc2[0][nt] = __builtin_amdgcn_mfma_f32_16x16x32_bf16(al0, whi, acc2[0][nt], 0, 0, 0);
            acc2[0][nt] = __builtin_amdgcn_mfma_f32_16x16x32_bf16(ah0, wlo, acc2[0][nt], 0, 0, 0);
            acc2[1][nt] = __builtin_amdgcn_mfma_f32_16x16x32_bf16(ah1, whi, acc2[1][nt], 0, 0, 0);
            acc2[1][nt] = __builtin_amdgcn_mfma_f32_16x16x32_bf16(al1, whi, acc2[1][nt], 0, 0, 0);
            acc2[1][nt] = __builtin_amdgcn_mfma_f32_16x16x32_bf16(ah1, wlo, acc2[1][nt], 0, 0, 0);
        }
    }

    float b2v[8];
#pragma unroll
    for (int nt = 0; nt < 8; ++nt) b2v[nt] = b2[nt * 16 + l15];

    float s[8], q[8];
#pragma unroll
    for (int nt = 0; nt < 8; ++nt) { s[nt] = 0.0f; q[nt] = 0.0f; }

#pragma unroll
    for (int m = 0; m < 2; ++m) {
#pragma unroll
        for (int rr = 0; rr < 4; ++rr) {
            int rg = row_base + m * 16 + l4 * 4 + rr;
            bool ok = rg < N_NODES;
#pragma unroll
            for (int nt = 0; nt < 8; ++nt) {
                float v = fmaxf(acc2[m][nt][rr] + b2v[nt], 0.0f);   // outer ReLU
                if (ok) {
                    h_raw[(size_t)rg * 128 + nt * 16 + l15] = v;
                    s[nt] += v;
                    q[nt] += v * v;
                }
            }
        }
    }
#pragma unroll
    for (int nt = 0; nt < 8; ++nt) {
        s[nt] += __shfl_xor(s[nt], 16); s[nt] += __shfl_xor(s[nt], 32);
        q[nt] += __shfl_xor(q[nt], 16); q[nt] += __shfl_xor(q[nt], 32);
    }
    if (l4 == 0) {
#pragma unroll
        for (int nt = 0; nt < 8; ++nt) {
            red_s[wave][nt * 16 + l15] = s[nt];
            red_q[wave][nt * 16 + l15] = q[nt];
        }
    }
    __syncthreads();
    if (t < 128) {
        part_s[blockIdx.x * 128 + t] = red_s[0][t] + red_s[1][t];
        part_q[blockIdx.x * 128 + t] = red_q[0][t] + red_q[1][t];
    }
}

__global__ void bn_reduce(const float* __restrict__ part_s, const float* __restrict__ part_q,
                          float* __restrict__ bn_sum, float* __restrict__ bn_sq, int nparts) {
    int t = threadIdx.x;
    if (t >= 128) return;
    const float* src = blockIdx.x ? part_q : part_s;
    float* dst = blockIdx.x ? bn_sq : bn_sum;
    float a = 0.0f;
    for (int p = 0; p < nparts; ++p) a += src[p * 128 + t];
    dst[t] = a;
}

// normalize in place (fp32)
__global__ void bn_apply(float* __restrict__ h,
                         const float* __restrict__ bn_sum, const float* __restrict__ bn_sq,
                         const float* __restrict__ gamma, const float* __restrict__ beta) {
    int i4 = blockIdx.x * 256 + threadIdx.x;
    if (i4 >= N_NODES * DIM / 4) return;
    float4 v = ((const float4*)h)[i4];
    int c0 = (i4 & 31) * 4;
    const float invN = 1.0f / (float)N_NODES;
    float* vp = (float*)&v;
#pragma unroll
    for (int j = 0; j < 4; ++j) {
        int c = c0 + j;
        float mean = bn_sum[c] * invN;
        float var = fmaxf(bn_sq[c] * invN - mean * mean, 0.0f);
        float inv = rsqrtf(var + BN_EPS);
        vp[j] = (vp[j] - mean) * inv * gamma[c] + beta[c];
    }
    ((float4*)h)[i4] = v;
}

// ---------------- launch ----------------

extern "C" void kernel_launch(void* const* d_in, const int* in_sizes, int n_in,
                              void* d_out, int out_size, void* d_ws, size_t ws_size,
                              hipStream_t stream) {
    const float* x     = (const float*)d_in[0];
    const int*   eidx  = (const int*)d_in[1];
    const float* W1    = (const float*)d_in[3];
    const float* b1    = (const float*)d_in[4];
    const float* W2    = (const float*)d_in[5];
    const float* b2    = (const float*)d_in[6];
    const float* gamma = (const float*)d_in[7];
    const float* beta  = (const float*)d_in[8];

    int n_edges = in_sizes[1] / 2;
    const int* src = eidx;
    const int* dst = eidx + n_edges;

    const int NBLK = (N_NODES + 63) / 64;    // 782 mlp blocks

    int* counts    = (int*)d_ws;                       // 50000
    int* offsets   = counts + N_NODES;                 // 50001
    int* cursor    = offsets + N_NODES + 1;            // 50000
    int* blocksums = cursor + N_NODES;                 // 256
    int* csr_src   = blocksums + 256;                  // n_edges
    float* part_s  = (float*)(csr_src + n_edges);      // NBLK*128
    float* part_q  = part_s + NBLK * 128;              // NBLK*128
    float* bn_sum  = part_q + NBLK * 128;              // 128
    float* bn_sq   = bn_sum + DIM;                     // 128
    size_t wp_off = (((size_t)(bn_sq + DIM) - (size_t)d_ws) + 15) & ~(size_t)15;
    unsigned short* wp = (unsigned short*)((char*)d_ws + wp_off);   // 5*2*32768 bf16 (hi+lo)

    float* out = (float*)d_out;
    // slot 0 doubles as bf16 hi/lo scratch until the final copy (exactly 25.6 MB)
    unsigned int* h_hi_u = (unsigned int*)d_out;                    // [N][64] uints
    unsigned int* h_lo_u = h_hi_u + (size_t)N_NODES * 64;
    const unsigned short* h_hi = (const unsigned short*)h_hi_u;
    const unsigned short* h_lo = (const unsigned short*)h_lo_u;

    // CSR build
    hipMemsetAsync(counts, 0, N_NODES * sizeof(int), stream);
    hist_kernel<<<(n_edges + 255) / 256, 256, 0, stream>>>(dst, n_edges, counts);
    int nb = (N_NODES + 255) / 256;
    scan_local<<<nb, 256, 0, stream>>>(counts, N_NODES, offsets, blocksums);
    scan_block<<<1, 256, 0, stream>>>(blocksums, nb);
    scan_add<<<nb, 256, 0, stream>>>(offsets, cursor, blocksums, N_NODES, n_edges);
    scatter_kernel<<<(n_edges + 255) / 256, 256, 0, stream>>>(src, dst, n_edges, cursor, csr_src);

    wpack_prep<<<(N_LAYERS * 2 * 16384 + 255) / 256, 256, 0, stream>>>(W1, W2, wp);

    const float* layer_in = x;
    for (int i = 0; i < N_LAYERS; ++i) {
        float* layer_out = out + (size_t)(1 + i) * N_NODES * DIM;
        agg_kernel<<<(N_NODES + 3) / 4, 256, 0, stream>>>(layer_in, csr_src, offsets,
                                                          h_hi_u, h_lo_u);
        mlp_mfma<<<NBLK, 128, 0, stream>>>(
            h_hi, h_lo,
            (const short8*)(wp + (size_t)(i * 2) * 32768), b1 + (size_t)i * DIM,
            (const short8*)(wp + (size_t)(i * 2 + 1) * 32768), b2 + (size_t)i * DIM,
            layer_out, part_s, part_q);
        bn_reduce<<<2, 128, 0, stream>>>(part_s, part_q, bn_sum, bn_sq, NBLK);
        bn_apply<<<(N_NODES * DIM / 4 + 255) / 256, 256, 0, stream>>>(
            layer_out, bn_sum, bn_sq, gamma + (size_t)i * DIM, beta + (size_t)i * DIM);
        layer_in = layer_out;
    }
    hipMemcpyAsync(out, out + (size_t)N_LAYERS * N_NODES * DIM,
                   (size_t)N_NODES * DIM * sizeof(float), hipMemcpyDeviceToDevice, stream);
}

// Round 4
// 741.251 us; speedup vs baseline: 2.2433x; 2.2433x over previous
//
#include <hip/hip_runtime.h>

#define N_NODES 50000
#define DIM 128
#define N_LAYERS 5
#define BN_EPS 1e-5f

typedef __attribute__((ext_vector_type(8))) short short8;
typedef __attribute__((ext_vector_type(4))) float f32x4;

__device__ __forceinline__ float bf2f(unsigned int u16) {
    union { unsigned int i; float f; } c; c.i = u16 << 16; return c.f;
}
__device__ __forceinline__ unsigned short f2bf(float f) {
    union { float f; unsigned int i; } c; c.f = f;
    unsigned int v = c.i + 0x7FFFu + ((c.i >> 16) & 1u);   // RNE
    return (unsigned short)(v >> 16);
}

// ---------------- CSR build ----------------

__global__ void hist_kernel(const int* __restrict__ dst, int n_edges, int* __restrict__ counts) {
    int e = blockIdx.x * 256 + threadIdx.x;
    if (e < n_edges) atomicAdd(&counts[dst[e]], 1);
}

__global__ void scan_local(const int* __restrict__ counts, int n,
                           int* __restrict__ offsets, int* __restrict__ blocksums) {
    __shared__ int temp[256];
    int t = threadIdx.x;
    int i = blockIdx.x * 256 + t;
    int v = (i < n) ? counts[i] : 0;
    temp[t] = v;
    __syncthreads();
    for (int off = 1; off < 256; off <<= 1) {
        int add = (t >= off) ? temp[t - off] : 0;
        __syncthreads();
        temp[t] += add;
        __syncthreads();
    }
    if (i < n) offsets[i] = temp[t] - v;
    if (t == 255) blocksums[blockIdx.x] = temp[255];
}

__global__ void scan_block(int* __restrict__ blocksums, int nb) {
    __shared__ int temp[256];
    int t = threadIdx.x;
    int v = (t < nb) ? blocksums[t] : 0;
    temp[t] = v;
    __syncthreads();
    for (int off = 1; off < 256; off <<= 1) {
        int add = (t >= off) ? temp[t - off] : 0;
        __syncthreads();
        temp[t] += add;
        __syncthreads();
    }
    if (t < nb) blocksums[t] = temp[t] - v;
}

__global__ void scan_add(int* __restrict__ offsets, int* __restrict__ cursor,
                         const int* __restrict__ blocksums, int n, int n_edges) {
    int i = blockIdx.x * 256 + threadIdx.x;
    if (i < n) {
        int val = offsets[i] + blocksums[blockIdx.x];
        offsets[i] = val;
        cursor[i] = val;
    }
    if (i == 0) offsets[n] = n_edges;
}

__global__ void scatter_kernel(const int* __restrict__ src, const int* __restrict__ dst,
                               int n_edges, int* __restrict__ cursor, int* __restrict__ csr_src) {
    int e = blockIdx.x * 256 + threadIdx.x;
    if (e < n_edges) {
        int p = atomicAdd(&cursor[dst[e]], 1);
        csr_src[p] = src[e];
    }
}

// ---------------- prep ----------------

// pack W1/W2 (all layers) into MFMA B-fragment order, hi+lo bf16 planes.
__global__ void wpack_prep(const float* __restrict__ W1, const float* __restrict__ W2,
                           unsigned short* __restrict__ wp) {
    int idx = blockIdx.x * 256 + threadIdx.x;
    if (idx >= N_LAYERS * 2 * 16384) return;
    int j    = idx & 7;
    int lane = (idx >> 3) & 63;
    int nt   = (idx >> 9) & 7;
    int ks   = (idx >> 12) & 3;
    int mat  = (idx >> 14) & 1;
    int lay  = idx >> 15;
    int l15 = lane & 15, l4 = lane >> 4;
    int col = nt * 16 + l15;
    int kp = ks * 32 + l4 * 8 + j;
    int k = mat ? ((kp & 7) * 16 + (kp >> 3)) : kp;
    const float* W = mat ? W2 : W1;
    float w = W[((size_t)lay * 128 + k) * 128 + col];
    unsigned short hi = f2bf(w);
    unsigned short lo = f2bf(w - bf2f(hi));
    size_t base = (size_t)(lay * 2 + mat) * 32768;
    size_t inner = (size_t)((ks * 8 + nt) * 64 + lane) * 8 + j;
    wp[base + inner] = hi;
    wp[base + 16384 + inner] = lo;
}

// ---------------- per-layer kernels ----------------

// one wave per node, fp32 accumulate; emit hi/lo bf16 planes for the MFMA MLP
__global__ void agg_kernel(const float* __restrict__ x, const int* __restrict__ csr_src,
                           const int* __restrict__ offsets,
                           unsigned int* __restrict__ h_hi_u, unsigned int* __restrict__ h_lo_u) {
    int wave = threadIdx.x >> 6;
    int lane = threadIdx.x & 63;
    int node = blockIdx.x * 4 + wave;
    if (node >= N_NODES) return;
    int beg = offsets[node], end = offsets[node + 1];
    float2 acc = ((const float2*)(x + (size_t)node * DIM))[lane];   // h = x + agg
    for (int e = beg; e < end; ++e) {
        int s = csr_src[e];
        float2 v = ((const float2*)(x + (size_t)s * DIM))[lane];
        acc.x += v.x;
        acc.y += v.y;
    }
    unsigned short hx = f2bf(acc.x), hy = f2bf(acc.y);
    unsigned short lx = f2bf(acc.x - bf2f(hx)), ly = f2bf(acc.y - bf2f(hy));
    h_hi_u[node * 64 + lane] = (unsigned int)hx | ((unsigned int)hy << 16);
    h_lo_u[node * 64 + lane] = (unsigned int)lx | ((unsigned int)ly << 16);
}

// fused MFMA MLP (bf16x2 split, 3-product): ReLU(h@W1+b1)@W2+b2 -> ReLU
// -> h_raw (fp32) + per-block BN partials
__global__ __launch_bounds__(128) void mlp_mfma(
        const unsigned short* __restrict__ h_hi, const unsigned short* __restrict__ h_lo,
        const short8* __restrict__ wp1, const float* __restrict__ b1,
        const short8* __restrict__ wp2, const float* __restrict__ b2,
        float* __restrict__ h_raw,
        float* __restrict__ part_s, float* __restrict__ part_q) {
    __shared__ unsigned short mid_hi[2][2][16][128];   // [wave][m][row][kp], XOR-swizzled
    __shared__ unsigned short mid_lo[2][2][16][128];
    __shared__ float red_s[2][128], red_q[2][128];
    int t = threadIdx.x, wave = t >> 6, l = t & 63;
    int l15 = l & 15, l4 = l >> 4;
    int row_base = blockIdx.x * 64 + wave * 32;

    int r0 = row_base + l15, r1 = r0 + 16;
    int cr0 = min(r0, N_NODES - 1), cr1 = min(r1, N_NODES - 1);
    const short8* ah0p = (const short8*)(h_hi + (size_t)cr0 * 128);
    const short8* ah1p = (const short8*)(h_hi + (size_t)cr1 * 128);
    const short8* al0p = (const short8*)(h_lo + (size_t)cr0 * 128);
    const short8* al1p = (const short8*)(h_lo + (size_t)cr1 * 128);

    const short8* wp1l = wp1 + 2048;   // lo plane
    const short8* wp2l = wp2 + 2048;

    f32x4 acc[2][8];
#pragma unroll
    for (int m = 0; m < 2; ++m)
#pragma unroll
        for (int nt = 0; nt < 8; ++nt) acc[m][nt] = (f32x4)0.0f;

#pragma unroll
    for (int ks = 0; ks < 4; ++ks) {
        short8 ah0 = ah0p[ks * 4 + l4];
        short8 ah1 = ah1p[ks * 4 + l4];
        short8 al0 = al0p[ks * 4 + l4];
        short8 al1 = al1p[ks * 4 + l4];
#pragma unroll
        for (int nt = 0; nt < 8; ++nt) {
            short8 whi = wp1[(ks * 8 + nt) * 64 + l];
            short8 wlo = wp1l[(ks * 8 + nt) * 64 + l];
            acc[0][nt] = __builtin_amdgcn_mfma_f32_16x16x32_bf16(ah0, whi, acc[0][nt], 0, 0, 0);
            acc[0][nt] = __builtin_amdgcn_mfma_f32_16x16x32_bf16(al0, whi, acc[0][nt], 0, 0, 0);
            acc[0][nt] = __builtin_amdgcn_mfma_f32_16x16x32_bf16(ah0, wlo, acc[0][nt], 0, 0, 0);
            acc[1][nt] = __builtin_amdgcn_mfma_f32_16x16x32_bf16(ah1, whi, acc[1][nt], 0, 0, 0);
            acc[1][nt] = __builtin_amdgcn_mfma_f32_16x16x32_bf16(al1, whi, acc[1][nt], 0, 0, 0);
            acc[1][nt] = __builtin_amdgcn_mfma_f32_16x16x32_bf16(ah1, wlo, acc[1][nt], 0, 0, 0);
        }
    }

    float b1v[8];
#pragma unroll
    for (int nt = 0; nt < 8; ++nt) b1v[nt] = b1[nt * 16 + l15];

#pragma unroll
    for (int m = 0; m < 2; ++m) {
#pragma unroll
        for (int rr = 0; rr < 4; ++rr) {
            int row = l4 * 4 + rr;
            short8 ph, pl;
#pragma unroll
            for (int nt = 0; nt < 8; ++nt) {
                float v = fmaxf(acc[m][nt][rr] + b1v[nt], 0.0f);
                unsigned short hv = f2bf(v);
                ph[nt] = (short)hv;
                pl[nt] = (short)f2bf(v - bf2f(hv));
            }
            int off = (l15 * 16) ^ ((row & 7) << 4);
            *(short8*)((char*)&mid_hi[wave][m][row][0] + off) = ph;
            *(short8*)((char*)&mid_lo[wave][m][row][0] + off) = pl;
        }
    }
    __syncthreads();

    f32x4 acc2[2][8];
#pragma unroll
    for (int m = 0; m < 2; ++m)
#pragma unroll
        for (int nt = 0; nt < 8; ++nt) acc2[m][nt] = (f32x4)0.0f;

#pragma unroll
    for (int ks = 0; ks < 4; ++ks) {
        int off = (ks * 64 + l4 * 16) ^ ((l15 & 7) << 4);
        short8 ah0 = *(const short8*)((char*)&mid_hi[wave][0][l15][0] + off);
        short8 ah1 = *(const short8*)((char*)&mid_hi[wave][1][l15][0] + off);
        short8 al0 = *(const short8*)((char*)&mid_lo[wave][0][l15][0] + off);
        short8 al1 = *(const short8*)((char*)&mid_lo[wave][1][l15][0] + off);
#pragma unroll
        for (int nt = 0; nt < 8; ++nt) {
            short8 whi = wp2[(ks * 8 + nt) * 64 + l];
            short8 wlo = wp2l[(ks * 8 + nt) * 64 + l];
            acc2[0][nt] = __builtin_amdgcn_mfma_f32_16x16x32_bf16(ah0, whi, acc2[0][nt], 0, 0, 0);
            acc2[0][nt] = __builtin_amdgcn_mfma_f32_16x16x32_bf16(al0, whi, acc2[0][nt], 0, 0, 0);
            acc2[0][nt] = __builtin_amdgcn_mfma_f32_16x16x32_bf16(ah0, wlo, acc2[0][nt], 0, 0, 0);
            acc2[1][nt] = __builtin_amdgcn_mfma_f32_16x16x32_bf16(ah1, whi, acc2[1][nt], 0, 0, 0);
            acc2[1][nt] = __builtin_amdgcn_mfma_f32_16x16x32_bf16(al1, whi, acc2[1][nt], 0, 0, 0);
            acc2[1][nt] = __builtin_amdgcn_mfma_f32_16x16x32_bf16(ah1, wlo, acc2[1][nt], 0, 0, 0);
        }
    }

    float b2v[8];
#pragma unroll
    for (int nt = 0; nt < 8; ++nt) b2v[nt] = b2[nt * 16 + l15];

    float s[8], q[8];
#pragma unroll
    for (int nt = 0; nt < 8; ++nt) { s[nt] = 0.0f; q[nt] = 0.0f; }

#pragma unroll
    for (int m = 0; m < 2; ++m) {
#pragma unroll
        for (int rr = 0; rr < 4; ++rr) {
            int rg = row_base + m * 16 + l4 * 4 + rr;
            bool ok = rg < N_NODES;
#pragma unroll
            for (int nt = 0; nt < 8; ++nt) {
                float v = fmaxf(acc2[m][nt][rr] + b2v[nt], 0.0f);   // outer ReLU
                if (ok) {
                    h_raw[(size_t)rg * 128 + nt * 16 + l15] = v;
                    s[nt] += v;
                    q[nt] += v * v;
                }
            }
        }
    }
#pragma unroll
    for (int nt = 0; nt < 8; ++nt) {
        s[nt] += __shfl_xor(s[nt], 16); s[nt] += __shfl_xor(s[nt], 32);
        q[nt] += __shfl_xor(q[nt], 16); q[nt] += __shfl_xor(q[nt], 32);
    }
    if (l4 == 0) {
#pragma unroll
        for (int nt = 0; nt < 8; ++nt) {
            red_s[wave][nt * 16 + l15] = s[nt];
            red_q[wave][nt * 16 + l15] = q[nt];
        }
    }
    __syncthreads();
    if (t < 128) {
        part_s[blockIdx.x * 128 + t] = red_s[0][t] + red_s[1][t];
        part_q[blockIdx.x * 128 + t] = red_q[0][t] + red_q[1][t];
    }
}

// 256 blocks: block b reduces channel (b&127) of (b>>7 ? part_q : part_s)
__global__ __launch_bounds__(256) void bn_reduce(
        const float* __restrict__ part_s, const float* __restrict__ part_q,
        float* __restrict__ bn_sum, float* __restrict__ bn_sq, int nparts) {
    __shared__ float red[256];
    int c = blockIdx.x & 127;
    const float* src = (blockIdx.x >> 7) ? part_q : part_s;
    float* dst = (blockIdx.x >> 7) ? bn_sq : bn_sum;
    float a = 0.0f;
    for (int p = threadIdx.x; p < nparts; p += 256) a += src[p * 128 + c];
    red[threadIdx.x] = a;
    __syncthreads();
    for (int s = 128; s > 0; s >>= 1) {
        if (threadIdx.x < s) red[threadIdx.x] += red[threadIdx.x + s];
        __syncthreads();
    }
    if (threadIdx.x == 0) dst[c] = red[0];
}

// normalize in place (fp32); optionally duplicate to a second buffer
__global__ void bn_apply(float* __restrict__ h,
                         const float* __restrict__ bn_sum, const float* __restrict__ bn_sq,
                         const float* __restrict__ gamma, const float* __restrict__ beta,
                         float4* __restrict__ dup) {
    int i4 = blockIdx.x * 256 + threadIdx.x;
    if (i4 >= N_NODES * DIM / 4) return;
    float4 v = ((const float4*)h)[i4];
    int c0 = (i4 & 31) * 4;
    const float invN = 1.0f / (float)N_NODES;
    float* vp = (float*)&v;
#pragma unroll
    for (int j = 0; j < 4; ++j) {
        int c = c0 + j;
        float mean = bn_sum[c] * invN;
        float var = fmaxf(bn_sq[c] * invN - mean * mean, 0.0f);
        float inv = rsqrtf(var + BN_EPS);
        vp[j] = (vp[j] - mean) * inv * gamma[c] + beta[c];
    }
    ((float4*)h)[i4] = v;
    if (dup) dup[i4] = v;
}

// ---------------- launch ----------------

extern "C" void kernel_launch(void* const* d_in, const int* in_sizes, int n_in,
                              void* d_out, int out_size, void* d_ws, size_t ws_size,
                              hipStream_t stream) {
    const float* x     = (const float*)d_in[0];
    const int*   eidx  = (const int*)d_in[1];
    const float* W1    = (const float*)d_in[3];
    const float* b1    = (const float*)d_in[4];
    const float* W2    = (const float*)d_in[5];
    const float* b2    = (const float*)d_in[6];
    const float* gamma = (const float*)d_in[7];
    const float* beta  = (const float*)d_in[8];

    int n_edges = in_sizes[1] / 2;
    const int* src = eidx;
    const int* dst = eidx + n_edges;

    const int NBLK = (N_NODES + 63) / 64;    // 782 mlp blocks

    int* counts    = (int*)d_ws;                       // 50000
    int* offsets   = counts + N_NODES;                 // 50001
    int* cursor    = offsets + N_NODES + 1;            // 50000
    int* blocksums = cursor + N_NODES;                 // 256
    int* csr_src   = blocksums + 256;                  // n_edges
    float* part_s  = (float*)(csr_src + n_edges);      // NBLK*128
    float* part_q  = part_s + NBLK * 128;              // NBLK*128
    float* bn_sum  = part_q + NBLK * 128;              // 128
    float* bn_sq   = bn_sum + DIM;                     // 128
    size_t wp_off = (((size_t)(bn_sq + DIM) - (size_t)d_ws) + 15) & ~(size_t)15;
    unsigned short* wp = (unsigned short*)((char*)d_ws + wp_off);   // 5*2*32768 bf16 (hi+lo)

    float* out = (float*)d_out;
    // slot 0 doubles as bf16 hi/lo scratch until the last layer writes it
    unsigned int* h_hi_u = (unsigned int*)d_out;                    // [N][64] uints
    unsigned int* h_lo_u = h_hi_u + (size_t)N_NODES * 64;
    const unsigned short* h_hi = (const unsigned short*)h_hi_u;
    const unsigned short* h_lo = (const unsigned short*)h_lo_u;

    // CSR build
    hipMemsetAsync(counts, 0, N_NODES * sizeof(int), stream);
    hist_kernel<<<(n_edges + 255) / 256, 256, 0, stream>>>(dst, n_edges, counts);
    int nb = (N_NODES + 255) / 256;
    scan_local<<<nb, 256, 0, stream>>>(counts, N_NODES, offsets, blocksums);
    scan_block<<<1, 256, 0, stream>>>(blocksums, nb);
    scan_add<<<nb, 256, 0, stream>>>(offsets, cursor, blocksums, N_NODES, n_edges);
    scatter_kernel<<<(n_edges + 255) / 256, 256, 0, stream>>>(src, dst, n_edges, cursor, csr_src);

    wpack_prep<<<(N_LAYERS * 2 * 16384 + 255) / 256, 256, 0, stream>>>(W1, W2, wp);

    const float* layer_in = x;
    for (int i = 0; i < N_LAYERS; ++i) {
        float* layer_out = out + (size_t)(1 + i) * N_NODES * DIM;
        agg_kernel<<<(N_NODES + 3) / 4, 256, 0, stream>>>(layer_in, csr_src, offsets,
                                                          h_hi_u, h_lo_u);
        mlp_mfma<<<NBLK, 128, 0, stream>>>(
            h_hi, h_lo,
            (const short8*)(wp + (size_t)(i * 2) * 32768), b1 + (size_t)i * DIM,
            (const short8*)(wp + (size_t)(i * 2 + 1) * 32768), b2 + (size_t)i * DIM,
            layer_out, part_s, part_q);
        bn_reduce<<<256, 256, 0, stream>>>(part_s, part_q, bn_sum, bn_sq, NBLK);
        // last layer: also write the final-h slot (out[0:N*D]) directly
        bn_apply<<<(N_NODES * DIM / 4 + 255) / 256, 256, 0, stream>>>(
            layer_out, bn_sum, bn_sq, gamma + (size_t)i * DIM, beta + (size_t)i * DIM,
            (i == N_LAYERS - 1) ? (float4*)out : (float4*)nullptr);
        layer_in = layer_out;
    }
}

// Round 5
// 606.256 us; speedup vs baseline: 2.7428x; 1.2227x over previous
//
#include <hip/hip_runtime.h>

#define N_NODES 50000
#define DIM 128
#define N_LAYERS 5
#define BN_EPS 1e-5f

typedef __attribute__((ext_vector_type(8))) short short8;
typedef __attribute__((ext_vector_type(4))) float f32x4;

__device__ __forceinline__ float bf2f(unsigned int u16) {
    union { unsigned int i; float f; } c; c.i = u16 << 16; return c.f;
}
__device__ __forceinline__ unsigned short f2bf(float f) {
    union { float f; unsigned int i; } c; c.f = f;
    unsigned int v = c.i + 0x7FFFu + ((c.i >> 16) & 1u);   // RNE
    return (unsigned short)(v >> 16);
}

// ---------------- CSR build ----------------

__global__ void hist_kernel(const int* __restrict__ dst, int n_edges, int* __restrict__ counts) {
    int e = blockIdx.x * 256 + threadIdx.x;
    if (e < n_edges) atomicAdd(&counts[dst[e]], 1);
}

__global__ void scan_local(const int* __restrict__ counts, int n,
                           int* __restrict__ offsets, int* __restrict__ blocksums) {
    __shared__ int temp[256];
    int t = threadIdx.x;
    int i = blockIdx.x * 256 + t;
    int v = (i < n) ? counts[i] : 0;
    temp[t] = v;
    __syncthreads();
    for (int off = 1; off < 256; off <<= 1) {
        int add = (t >= off) ? temp[t - off] : 0;
        __syncthreads();
        temp[t] += add;
        __syncthreads();
    }
    if (i < n) offsets[i] = temp[t] - v;
    if (t == 255) blocksums[blockIdx.x] = temp[255];
}

__global__ void scan_block(int* __restrict__ blocksums, int nb) {
    __shared__ int temp[256];
    int t = threadIdx.x;
    int v = (t < nb) ? blocksums[t] : 0;
    temp[t] = v;
    __syncthreads();
    for (int off = 1; off < 256; off <<= 1) {
        int add = (t >= off) ? temp[t - off] : 0;
        __syncthreads();
        temp[t] += add;
        __syncthreads();
    }
    if (t < nb) blocksums[t] = temp[t] - v;
}

__global__ void scan_add(int* __restrict__ offsets, int* __restrict__ cursor,
                         const int* __restrict__ blocksums, int n, int n_edges) {
    int i = blockIdx.x * 256 + threadIdx.x;
    if (i < n) {
        int val = offsets[i] + blocksums[blockIdx.x];
        offsets[i] = val;
        cursor[i] = val;
    }
    if (i == 0) offsets[n] = n_edges;
}

__global__ void scatter_kernel(const int* __restrict__ src, const int* __restrict__ dst,
                               int n_edges, int* __restrict__ cursor, int* __restrict__ csr_src) {
    int e = blockIdx.x * 256 + threadIdx.x;
    if (e < n_edges) {
        int p = atomicAdd(&cursor[dst[e]], 1);
        csr_src[p] = src[e];
    }
}

// ---------------- prep ----------------

// pack W1/W2 (all layers) into MFMA B-fragment order, hi+lo bf16 planes.
__global__ void wpack_prep(const float* __restrict__ W1, const float* __restrict__ W2,
                           unsigned short* __restrict__ wp) {
    int idx = blockIdx.x * 256 + threadIdx.x;
    if (idx >= N_LAYERS * 2 * 16384) return;
    int j    = idx & 7;
    int lane = (idx >> 3) & 63;
    int nt   = (idx >> 9) & 7;
    int ks   = (idx >> 12) & 3;
    int mat  = (idx >> 14) & 1;
    int lay  = idx >> 15;
    int l15 = lane & 15, l4 = lane >> 4;
    int col = nt * 16 + l15;
    int kp = ks * 32 + l4 * 8 + j;
    int k = mat ? ((kp & 7) * 16 + (kp >> 3)) : kp;
    const float* W = mat ? W2 : W1;
    float w = W[((size_t)lay * 128 + k) * 128 + col];
    unsigned short hi = f2bf(w);
    unsigned short lo = f2bf(w - bf2f(hi));
    size_t base = (size_t)(lay * 2 + mat) * 32768;
    size_t inner = (size_t)((ks * 8 + nt) * 64 + lane) * 8 + j;
    wp[base + inner] = hi;
    wp[base + 16384 + inner] = lo;
}

// ---------------- per-layer kernels ----------------

// one wave per node, fp32 accumulate, 8-deep edge software pipeline;
// emits hi/lo bf16 planes for the MFMA MLP
__global__ void agg_kernel(const float* __restrict__ x, const int* __restrict__ csr_src,
                           const int* __restrict__ offsets,
                           unsigned int* __restrict__ h_hi_u, unsigned int* __restrict__ h_lo_u) {
    int wave = threadIdx.x >> 6;
    int lane = threadIdx.x & 63;
    int node = blockIdx.x * 4 + wave;
    if (node >= N_NODES) return;
    int beg = offsets[node], end = offsets[node + 1];
    const float2* x2 = (const float2*)x;
    float2 acc = x2[(size_t)node * 64 + lane];   // h = x + agg

    for (int e = beg; e < end; e += 8) {
        // batch the 8 (wave-uniform) indices; clamp tail to a safe address
        int s[8];
#pragma unroll
        for (int i = 0; i < 8; ++i) s[i] = csr_src[min(e + i, end - 1)];
        float2 v[8];
#pragma unroll
        for (int i = 0; i < 8; ++i) v[i] = x2[(size_t)s[i] * 64 + lane];
#pragma unroll
        for (int i = 0; i < 8; ++i) {
            float w = (e + i < end) ? 1.0f : 0.0f;   // mask tail (no divergence)
            acc.x = fmaf(v[i].x, w, acc.x);
            acc.y = fmaf(v[i].y, w, acc.y);
        }
    }

    unsigned short hx = f2bf(acc.x), hy = f2bf(acc.y);
    unsigned short lx = f2bf(acc.x - bf2f(hx)), ly = f2bf(acc.y - bf2f(hy));
    h_hi_u[node * 64 + lane] = (unsigned int)hx | ((unsigned int)hy << 16);
    h_lo_u[node * 64 + lane] = (unsigned int)lx | ((unsigned int)ly << 16);
}

// fused MFMA MLP (bf16x2 split, 3-product): ReLU(h@W1+b1)@W2+b2 -> ReLU
// -> h_raw (fp32) + per-block BN partials
__global__ __launch_bounds__(128) void mlp_mfma(
        const unsigned short* __restrict__ h_hi, const unsigned short* __restrict__ h_lo,
        const short8* __restrict__ wp1, const float* __restrict__ b1,
        const short8* __restrict__ wp2, const float* __restrict__ b2,
        float* __restrict__ h_raw,
        float* __restrict__ part_s, float* __restrict__ part_q) {
    __shared__ unsigned short mid_hi[2][2][16][128];   // [wave][m][row][kp], XOR-swizzled
    __shared__ unsigned short mid_lo[2][2][16][128];
    __shared__ float red_s[2][128], red_q[2][128];
    int t = threadIdx.x, wave = t >> 6, l = t & 63;
    int l15 = l & 15, l4 = l >> 4;
    int row_base = blockIdx.x * 64 + wave * 32;

    int r0 = row_base + l15, r1 = r0 + 16;
    int cr0 = min(r0, N_NODES - 1), cr1 = min(r1, N_NODES - 1);
    const short8* ah0p = (const short8*)(h_hi + (size_t)cr0 * 128);
    const short8* ah1p = (const short8*)(h_hi + (size_t)cr1 * 128);
    const short8* al0p = (const short8*)(h_lo + (size_t)cr0 * 128);
    const short8* al1p = (const short8*)(h_lo + (size_t)cr1 * 128);

    const short8* wp1l = wp1 + 2048;   // lo plane
    const short8* wp2l = wp2 + 2048;

    f32x4 acc[2][8];
#pragma unroll
    for (int m = 0; m < 2; ++m)
#pragma unroll
        for (int nt = 0; nt < 8; ++nt) acc[m][nt] = (f32x4)0.0f;

#pragma unroll
    for (int ks = 0; ks < 4; ++ks) {
        short8 ah0 = ah0p[ks * 4 + l4];
        short8 ah1 = ah1p[ks * 4 + l4];
        short8 al0 = al0p[ks * 4 + l4];
        short8 al1 = al1p[ks * 4 + l4];
#pragma unroll
        for (int nt = 0; nt < 8; ++nt) {
            short8 whi = wp1[(ks * 8 + nt) * 64 + l];
            short8 wlo = wp1l[(ks * 8 + nt) * 64 + l];
            acc[0][nt] = __builtin_amdgcn_mfma_f32_16x16x32_bf16(ah0, whi, acc[0][nt], 0, 0, 0);
            acc[0][nt] = __builtin_amdgcn_mfma_f32_16x16x32_bf16(al0, whi, acc[0][nt], 0, 0, 0);
            acc[0][nt] = __builtin_amdgcn_mfma_f32_16x16x32_bf16(ah0, wlo, acc[0][nt], 0, 0, 0);
            acc[1][nt] = __builtin_amdgcn_mfma_f32_16x16x32_bf16(ah1, whi, acc[1][nt], 0, 0, 0);
            acc[1][nt] = __builtin_amdgcn_mfma_f32_16x16x32_bf16(al1, whi, acc[1][nt], 0, 0, 0);
            acc[1][nt] = __builtin_amdgcn_mfma_f32_16x16x32_bf16(ah1, wlo, acc[1][nt], 0, 0, 0);
        }
    }

    float b1v[8];
#pragma unroll
    for (int nt = 0; nt < 8; ++nt) b1v[nt] = b1[nt * 16 + l15];

#pragma unroll
    for (int m = 0; m < 2; ++m) {
#pragma unroll
        for (int rr = 0; rr < 4; ++rr) {
            int row = l4 * 4 + rr;
            short8 ph, pl;
#pragma unroll
            for (int nt = 0; nt < 8; ++nt) {
                float v = fmaxf(acc[m][nt][rr] + b1v[nt], 0.0f);
                unsigned short hv = f2bf(v);
                ph[nt] = (short)hv;
                pl[nt] = (short)f2bf(v - bf2f(hv));
            }
            int off = (l15 * 16) ^ ((row & 7) << 4);
            *(short8*)((char*)&mid_hi[wave][m][row][0] + off) = ph;
            *(short8*)((char*)&mid_lo[wave][m][row][0] + off) = pl;
        }
    }
    __syncthreads();

    f32x4 acc2[2][8];
#pragma unroll
    for (int m = 0; m < 2; ++m)
#pragma unroll
        for (int nt = 0; nt < 8; ++nt) acc2[m][nt] = (f32x4)0.0f;

#pragma unroll
    for (int ks = 0; ks < 4; ++ks) {
        int off = (ks * 64 + l4 * 16) ^ ((l15 & 7) << 4);
        short8 ah0 = *(const short8*)((char*)&mid_hi[wave][0][l15][0] + off);
        short8 ah1 = *(const short8*)((char*)&mid_hi[wave][1][l15][0] + off);
        short8 al0 = *(const short8*)((char*)&mid_lo[wave][0][l15][0] + off);
        short8 al1 = *(const short8*)((char*)&mid_lo[wave][1][l15][0] + off);
#pragma unroll
        for (int nt = 0; nt < 8; ++nt) {
            short8 whi = wp2[(ks * 8 + nt) * 64 + l];
            short8 wlo = wp2l[(ks * 8 + nt) * 64 + l];
            acc2[0][nt] = __builtin_amdgcn_mfma_f32_16x16x32_bf16(ah0, whi, acc2[0][nt], 0, 0, 0);
            acc2[0][nt] = __builtin_amdgcn_mfma_f32_16x16x32_bf16(al0, whi, acc2[0][nt], 0, 0, 0);
            acc2[0][nt] = __builtin_amdgcn_mfma_f32_16x16x32_bf16(ah0, wlo, acc2[0][nt], 0, 0, 0);
            acc2[1][nt] = __builtin_amdgcn_mfma_f32_16x16x32_bf16(ah1, whi, acc2[1][nt], 0, 0, 0);
            acc2[1][nt] = __builtin_amdgcn_mfma_f32_16x16x32_bf16(al1, whi, acc2[1][nt], 0, 0, 0);
            acc2[1][nt] = __builtin_amdgcn_mfma_f32_16x16x32_bf16(ah1, wlo, acc2[1][nt], 0, 0, 0);
        }
    }

    float b2v[8];
#pragma unroll
    for (int nt = 0; nt < 8; ++nt) b2v[nt] = b2[nt * 16 + l15];

    float s[8], q[8];
#pragma unroll
    for (int nt = 0; nt < 8; ++nt) { s[nt] = 0.0f; q[nt] = 0.0f; }

#pragma unroll
    for (int m = 0; m < 2; ++m) {
#pragma unroll
        for (int rr = 0; rr < 4; ++rr) {
            int rg = row_base + m * 16 + l4 * 4 + rr;
            bool ok = rg < N_NODES;
#pragma unroll
            for (int nt = 0; nt < 8; ++nt) {
                float v = fmaxf(acc2[m][nt][rr] + b2v[nt], 0.0f);   // outer ReLU
                if (ok) {
                    h_raw[(size_t)rg * 128 + nt * 16 + l15] = v;
                    s[nt] += v;
                    q[nt] += v * v;
                }
            }
        }
    }
#pragma unroll
    for (int nt = 0; nt < 8; ++nt) {
        s[nt] += __shfl_xor(s[nt], 16); s[nt] += __shfl_xor(s[nt], 32);
        q[nt] += __shfl_xor(q[nt], 16); q[nt] += __shfl_xor(q[nt], 32);
    }
    if (l4 == 0) {
#pragma unroll
        for (int nt = 0; nt < 8; ++nt) {
            red_s[wave][nt * 16 + l15] = s[nt];
            red_q[wave][nt * 16 + l15] = q[nt];
        }
    }
    __syncthreads();
    if (t < 128) {
        part_s[blockIdx.x * 128 + t] = red_s[0][t] + red_s[1][t];
        part_q[blockIdx.x * 128 + t] = red_q[0][t] + red_q[1][t];
    }
}

// 256 blocks: block b reduces channel (b&127) of (b>>7 ? part_q : part_s)
__global__ __launch_bounds__(256) void bn_reduce(
        const float* __restrict__ part_s, const float* __restrict__ part_q,
        float* __restrict__ bn_sum, float* __restrict__ bn_sq, int nparts) {
    __shared__ float red[256];
    int c = blockIdx.x & 127;
    const float* src = (blockIdx.x >> 7) ? part_q : part_s;
    float* dst = (blockIdx.x >> 7) ? bn_sq : bn_sum;
    float a = 0.0f;
    for (int p = threadIdx.x; p < nparts; p += 256) a += src[p * 128 + c];
    red[threadIdx.x] = a;
    __syncthreads();
    for (int s = 128; s > 0; s >>= 1) {
        if (threadIdx.x < s) red[threadIdx.x] += red[threadIdx.x + s];
        __syncthreads();
    }
    if (threadIdx.x == 0) dst[c] = red[0];
}

// normalize in place (fp32); optionally duplicate to a second buffer
__global__ void bn_apply(float* __restrict__ h,
                         const float* __restrict__ bn_sum, const float* __restrict__ bn_sq,
                         const float* __restrict__ gamma, const float* __restrict__ beta,
                         float4* __restrict__ dup) {
    int i4 = blockIdx.x * 256 + threadIdx.x;
    if (i4 >= N_NODES * DIM / 4) return;
    float4 v = ((const float4*)h)[i4];
    int c0 = (i4 & 31) * 4;
    const float invN = 1.0f / (float)N_NODES;
    float* vp = (float*)&v;
#pragma unroll
    for (int j = 0; j < 4; ++j) {
        int c = c0 + j;
        float mean = bn_sum[c] * invN;
        float var = fmaxf(bn_sq[c] * invN - mean * mean, 0.0f);
        float inv = rsqrtf(var + BN_EPS);
        vp[j] = (vp[j] - mean) * inv * gamma[c] + beta[c];
    }
    ((float4*)h)[i4] = v;
    if (dup) dup[i4] = v;
}

// ---------------- launch ----------------

extern "C" void kernel_launch(void* const* d_in, const int* in_sizes, int n_in,
                              void* d_out, int out_size, void* d_ws, size_t ws_size,
                              hipStream_t stream) {
    const float* x     = (const float*)d_in[0];
    const int*   eidx  = (const int*)d_in[1];
    const float* W1    = (const float*)d_in[3];
    const float* b1    = (const float*)d_in[4];
    const float* W2    = (const float*)d_in[5];
    const float* b2    = (const float*)d_in[6];
    const float* gamma = (const float*)d_in[7];
    const float* beta  = (const float*)d_in[8];

    int n_edges = in_sizes[1] / 2;
    const int* src = eidx;
    const int* dst = eidx + n_edges;

    const int NBLK = (N_NODES + 63) / 64;    // 782 mlp blocks

    int* counts    = (int*)d_ws;                       // 50000
    int* offsets   = counts + N_NODES;                 // 50001
    int* cursor    = offsets + N_NODES + 1;            // 50000
    int* blocksums = cursor + N_NODES;                 // 256
    int* csr_src   = blocksums + 256;                  // n_edges
    float* part_s  = (float*)(csr_src + n_edges);      // NBLK*128
    float* part_q  = part_s + NBLK * 128;              // NBLK*128
    float* bn_sum  = part_q + NBLK * 128;              // 128
    float* bn_sq   = bn_sum + DIM;                     // 128
    size_t wp_off = (((size_t)(bn_sq + DIM) - (size_t)d_ws) + 15) & ~(size_t)15;
    unsigned short* wp = (unsigned short*)((char*)d_ws + wp_off);   // 5*2*32768 bf16 (hi+lo)

    float* out = (float*)d_out;
    // slot 0 doubles as bf16 hi/lo scratch until the last layer writes it
    unsigned int* h_hi_u = (unsigned int*)d_out;                    // [N][64] uints
    unsigned int* h_lo_u = h_hi_u + (size_t)N_NODES * 64;
    const unsigned short* h_hi = (const unsigned short*)h_hi_u;
    const unsigned short* h_lo = (const unsigned short*)h_lo_u;

    // CSR build
    hipMemsetAsync(counts, 0, N_NODES * sizeof(int), stream);
    hist_kernel<<<(n_edges + 255) / 256, 256, 0, stream>>>(dst, n_edges, counts);
    int nb = (N_NODES + 255) / 256;
    scan_local<<<nb, 256, 0, stream>>>(counts, N_NODES, offsets, blocksums);
    scan_block<<<1, 256, 0, stream>>>(blocksums, nb);
    scan_add<<<nb, 256, 0, stream>>>(offsets, cursor, blocksums, N_NODES, n_edges);
    scatter_kernel<<<(n_edges + 255) / 256, 256, 0, stream>>>(src, dst, n_edges, cursor, csr_src);

    wpack_prep<<<(N_LAYERS * 2 * 16384 + 255) / 256, 256, 0, stream>>>(W1, W2, wp);

    const float* layer_in = x;
    for (int i = 0; i < N_LAYERS; ++i) {
        float* layer_out = out + (size_t)(1 + i) * N_NODES * DIM;
        agg_kernel<<<(N_NODES + 3) / 4, 256, 0, stream>>>(layer_in, csr_src, offsets,
                                                          h_hi_u, h_lo_u);
        mlp_mfma<<<NBLK, 128, 0, stream>>>(
            h_hi, h_lo,
            (const short8*)(wp + (size_t)(i * 2) * 32768), b1 + (size_t)i * DIM,
            (const short8*)(wp + (size_t)(i * 2 + 1) * 32768), b2 + (size_t)i * DIM,
            layer_out, part_s, part_q);
        bn_reduce<<<256, 256, 0, stream>>>(part_s, part_q, bn_sum, bn_sq, NBLK);
        // last layer: also write the final-h slot (out[0:N*D]) directly
        bn_apply<<<(N_NODES * DIM / 4 + 255) / 256, 256, 0, stream>>>(
            layer_out, bn_sum, bn_sq, gamma + (size_t)i * DIM, beta + (size_t)i * DIM,
            (i == N_LAYERS - 1) ? (float4*)out : (float4*)nullptr);
        layer_in = layer_out;
    }
}

// Round 7
// 598.880 us; speedup vs baseline: 2.7765x; 1.0123x over previous
//
#include <hip/hip_runtime.h>

#define N_NODES 50000
#define DIM 128
#define N_LAYERS 5
#define BN_EPS 1e-5f

typedef __attribute__((ext_vector_type(8))) short short8;
typedef __attribute__((ext_vector_type(4))) float f32x4;

__device__ __forceinline__ float bf2f(unsigned int u16) {
    union { unsigned int i; float f; } c; c.i = u16 << 16; return c.f;
}
__device__ __forceinline__ unsigned short f2bf(float f) {
    union { float f; unsigned int i; } c; c.f = f;
    unsigned int v = c.i + 0x7FFFu + ((c.i >> 16) & 1u);   // RNE
    return (unsigned short)(v >> 16);
}

// ---------------- CSR build ----------------

__global__ void hist_kernel(const int* __restrict__ dst, int n_edges, int* __restrict__ counts) {
    int e = blockIdx.x * 256 + threadIdx.x;
    if (e < n_edges) atomicAdd(&counts[dst[e]], 1);
}

__global__ void scan_local(const int* __restrict__ counts, int n,
                           int* __restrict__ offsets, int* __restrict__ blocksums) {
    __shared__ int temp[256];
    int t = threadIdx.x;
    int i = blockIdx.x * 256 + t;
    int v = (i < n) ? counts[i] : 0;
    temp[t] = v;
    __syncthreads();
    for (int off = 1; off < 256; off <<= 1) {
        int add = (t >= off) ? temp[t - off] : 0;
        __syncthreads();
        temp[t] += add;
        __syncthreads();
    }
    if (i < n) offsets[i] = temp[t] - v;
    if (t == 255) blocksums[blockIdx.x] = temp[255];
}

__global__ void scan_block(int* __restrict__ blocksums, int nb) {
    __shared__ int temp[256];
    int t = threadIdx.x;
    int v = (t < nb) ? blocksums[t] : 0;
    temp[t] = v;
    __syncthreads();
    for (int off = 1; off < 256; off <<= 1) {
        int add = (t >= off) ? temp[t - off] : 0;
        __syncthreads();
        temp[t] += add;
        __syncthreads();
    }
    if (t < nb) blocksums[t] = temp[t] - v;
}

__global__ void scan_add(int* __restrict__ offsets, int* __restrict__ cursor,
                         const int* __restrict__ blocksums, int n, int n_edges) {
    int i = blockIdx.x * 256 + threadIdx.x;
    if (i < n) {
        int val = offsets[i] + blocksums[blockIdx.x];
        offsets[i] = val;
        cursor[i] = val;
    }
    if (i == 0) offsets[n] = n_edges;
}

__global__ void scatter_kernel(const int* __restrict__ src, const int* __restrict__ dst,
                               int n_edges, int* __restrict__ cursor, int* __restrict__ csr_src) {
    int e = blockIdx.x * 256 + threadIdx.x;
    if (e < n_edges) {
        int p = atomicAdd(&cursor[dst[e]], 1);
        csr_src[p] = src[e];
    }
}

// ---------------- prep ----------------

// pack W1/W2 (all layers) into MFMA B-fragment order, hi+lo bf16 planes.
__global__ void wpack_prep(const float* __restrict__ W1, const float* __restrict__ W2,
                           unsigned short* __restrict__ wp) {
    int idx = blockIdx.x * 256 + threadIdx.x;
    if (idx >= N_LAYERS * 2 * 16384) return;
    int j    = idx & 7;
    int lane = (idx >> 3) & 63;
    int nt   = (idx >> 9) & 7;
    int ks   = (idx >> 12) & 3;
    int mat  = (idx >> 14) & 1;
    int lay  = idx >> 15;
    int l15 = lane & 15, l4 = lane >> 4;
    int col = nt * 16 + l15;
    int kp = ks * 32 + l4 * 8 + j;
    int k = mat ? ((kp & 7) * 16 + (kp >> 3)) : kp;
    const float* W = mat ? W2 : W1;
    float w = W[((size_t)lay * 128 + k) * 128 + col];
    unsigned short hi = f2bf(w);
    unsigned short lo = f2bf(w - bf2f(hi));
    size_t base = (size_t)(lay * 2 + mat) * 32768;
    size_t inner = (size_t)((ks * 8 + nt) * 64 + lane) * 8 + j;
    wp[base + inner] = hi;
    wp[base + 16384 + inner] = lo;
}

// ---------------- per-layer kernels ----------------

// one wave per node; fp32 float4 gathers, 2 edges per instruction
// (half-wave per edge), depth-8 pipeline = 16 rows in flight.
// Emits hi/lo bf16 planes for the MFMA MLP.
__global__ void agg_kernel(const float* __restrict__ x, const int* __restrict__ csr_src,
                           const int* __restrict__ offsets,
                           unsigned int* __restrict__ h_hi_u, unsigned int* __restrict__ h_lo_u) {
    int wave = threadIdx.x >> 6;
    int l = threadIdx.x & 63;
    int node = blockIdx.x * 4 + wave;
    if (node >= N_NODES) return;
    int half = l >> 5;       // which edge of the pair
    int d4 = l & 31;         // which float4 chunk of the 128-dim row
    int beg = offsets[node], end = offsets[node + 1];
    const float4* x4 = (const float4*)x;

    float4 acc = make_float4(0.f, 0.f, 0.f, 0.f);
    if (half == 0) acc = x4[(size_t)node * 32 + d4];   // self term once

    for (int e = beg; e < end; e += 16) {
        int s[8];
#pragma unroll
        for (int i = 0; i < 8; ++i) s[i] = csr_src[min(e + 2 * i + half, end - 1)];
        float4 v[8];
#pragma unroll
        for (int i = 0; i < 8; ++i) v[i] = x4[(size_t)s[i] * 32 + d4];
#pragma unroll
        for (int i = 0; i < 8; ++i) {
            float w = (e + 2 * i + half < end) ? 1.0f : 0.0f;   // mask tail
            acc.x = fmaf(v[i].x, w, acc.x);
            acc.y = fmaf(v[i].y, w, acc.y);
            acc.z = fmaf(v[i].z, w, acc.z);
            acc.w = fmaf(v[i].w, w, acc.w);
        }
    }

    // combine the two half-wave partials (lane l <-> l^32 hold same dims)
    acc.x += __shfl_xor(acc.x, 32);
    acc.y += __shfl_xor(acc.y, 32);
    acc.z += __shfl_xor(acc.z, 32);
    acc.w += __shfl_xor(acc.w, 32);

    // half 0 writes hi plane, half 1 writes lo plane (uint2 per lane)
    unsigned short h0 = f2bf(acc.x), h1 = f2bf(acc.y);
    unsigned short h2 = f2bf(acc.z), h3 = f2bf(acc.w);
    if (half == 0) {
        uint2 hv;
        hv.x = (unsigned int)h0 | ((unsigned int)h1 << 16);
        hv.y = (unsigned int)h2 | ((unsigned int)h3 << 16);
        ((uint2*)h_hi_u)[(size_t)node * 32 + d4] = hv;
    } else {
        unsigned short l0 = f2bf(acc.x - bf2f(h0)), l1 = f2bf(acc.y - bf2f(h1));
        unsigned short l2 = f2bf(acc.z - bf2f(h2)), l3 = f2bf(acc.w - bf2f(h3));
        uint2 lv;
        lv.x = (unsigned int)l0 | ((unsigned int)l1 << 16);
        lv.y = (unsigned int)l2 | ((unsigned int)l3 << 16);
        ((uint2*)h_lo_u)[(size_t)node * 32 + d4] = lv;
    }
}

// fused MFMA MLP (bf16x2 split, 3-product): ReLU(h@W1+b1)@W2+b2 -> ReLU
// -> h_raw (fp32) + per-block BN partials
__global__ __launch_bounds__(128) void mlp_mfma(
        const unsigned short* __restrict__ h_hi, const unsigned short* __restrict__ h_lo,
        const short8* __restrict__ wp1, const float* __restrict__ b1,
        const short8* __restrict__ wp2, const float* __restrict__ b2,
        float* __restrict__ h_raw,
        float* __restrict__ part_s, float* __restrict__ part_q) {
    __shared__ unsigned short mid_hi[2][2][16][128];   // [wave][m][row][kp], XOR-swizzled
    __shared__ unsigned short mid_lo[2][2][16][128];
    __shared__ float red_s[2][128], red_q[2][128];
    int t = threadIdx.x, wave = t >> 6, l = t & 63;
    int l15 = l & 15, l4 = l >> 4;
    int row_base = blockIdx.x * 64 + wave * 32;

    int r0 = row_base + l15, r1 = r0 + 16;
    int cr0 = min(r0, N_NODES - 1), cr1 = min(r1, N_NODES - 1);
    const short8* ah0p = (const short8*)(h_hi + (size_t)cr0 * 128);
    const short8* ah1p = (const short8*)(h_hi + (size_t)cr1 * 128);
    const short8* al0p = (const short8*)(h_lo + (size_t)cr0 * 128);
    const short8* al1p = (const short8*)(h_lo + (size_t)cr1 * 128);

    const short8* wp1l = wp1 + 2048;   // lo plane
    const short8* wp2l = wp2 + 2048;

    f32x4 acc[2][8];
#pragma unroll
    for (int m = 0; m < 2; ++m)
#pragma unroll
        for (int nt = 0; nt < 8; ++nt) acc[m][nt] = (f32x4)0.0f;

#pragma unroll
    for (int ks = 0; ks < 4; ++ks) {
        short8 ah0 = ah0p[ks * 4 + l4];
        short8 ah1 = ah1p[ks * 4 + l4];
        short8 al0 = al0p[ks * 4 + l4];
        short8 al1 = al1p[ks * 4 + l4];
#pragma unroll
        for (int nt = 0; nt < 8; ++nt) {
            short8 whi = wp1[(ks * 8 + nt) * 64 + l];
            short8 wlo = wp1l[(ks * 8 + nt) * 64 + l];
            acc[0][nt] = __builtin_amdgcn_mfma_f32_16x16x32_bf16(ah0, whi, acc[0][nt], 0, 0, 0);
            acc[0][nt] = __builtin_amdgcn_mfma_f32_16x16x32_bf16(al0, whi, acc[0][nt], 0, 0, 0);
            acc[0][nt] = __builtin_amdgcn_mfma_f32_16x16x32_bf16(ah0, wlo, acc[0][nt], 0, 0, 0);
            acc[1][nt] = __builtin_amdgcn_mfma_f32_16x16x32_bf16(ah1, whi, acc[1][nt], 0, 0, 0);
            acc[1][nt] = __builtin_amdgcn_mfma_f32_16x16x32_bf16(al1, whi, acc[1][nt], 0, 0, 0);
            acc[1][nt] = __builtin_amdgcn_mfma_f32_16x16x32_bf16(ah1, wlo, acc[1][nt], 0, 0, 0);
        }
    }

    float b1v[8];
#pragma unroll
    for (int nt = 0; nt < 8; ++nt) b1v[nt] = b1[nt * 16 + l15];

#pragma unroll
    for (int m = 0; m < 2; ++m) {
#pragma unroll
        for (int rr = 0; rr < 4; ++rr) {
            int row = l4 * 4 + rr;
            short8 ph, pl;
#pragma unroll
            for (int nt = 0; nt < 8; ++nt) {
                float v = fmaxf(acc[m][nt][rr] + b1v[nt], 0.0f);
                unsigned short hv = f2bf(v);
                ph[nt] = (short)hv;
                pl[nt] = (short)f2bf(v - bf2f(hv));
            }
            int off = (l15 * 16) ^ ((row & 7) << 4);
            *(short8*)((char*)&mid_hi[wave][m][row][0] + off) = ph;
            *(short8*)((char*)&mid_lo[wave][m][row][0] + off) = pl;
        }
    }
    __syncthreads();

    f32x4 acc2[2][8];
#pragma unroll
    for (int m = 0; m < 2; ++m)
#pragma unroll
        for (int nt = 0; nt < 8; ++nt) acc2[m][nt] = (f32x4)0.0f;

#pragma unroll
    for (int ks = 0; ks < 4; ++ks) {
        int off = (ks * 64 + l4 * 16) ^ ((l15 & 7) << 4);
        short8 ah0 = *(const short8*)((char*)&mid_hi[wave][0][l15][0] + off);
        short8 ah1 = *(const short8*)((char*)&mid_hi[wave][1][l15][0] + off);
        short8 al0 = *(const short8*)((char*)&mid_lo[wave][0][l15][0] + off);
        short8 al1 = *(const short8*)((char*)&mid_lo[wave][1][l15][0] + off);
#pragma unroll
        for (int nt = 0; nt < 8; ++nt) {
            short8 whi = wp2[(ks * 8 + nt) * 64 + l];
            short8 wlo = wp2l[(ks * 8 + nt) * 64 + l];
            acc2[0][nt] = __builtin_amdgcn_mfma_f32_16x16x32_bf16(ah0, whi, acc2[0][nt], 0, 0, 0);
            acc2[0][nt] = __builtin_amdgcn_mfma_f32_16x16x32_bf16(al0, whi, acc2[0][nt], 0, 0, 0);
            acc2[0][nt] = __builtin_amdgcn_mfma_f32_16x16x32_bf16(ah0, wlo, acc2[0][nt], 0, 0, 0);
            acc2[1][nt] = __builtin_amdgcn_mfma_f32_16x16x32_bf16(ah1, whi, acc2[1][nt], 0, 0, 0);
            acc2[1][nt] = __builtin_amdgcn_mfma_f32_16x16x32_bf16(al1, whi, acc2[1][nt], 0, 0, 0);
            acc2[1][nt] = __builtin_amdgcn_mfma_f32_16x16x32_bf16(ah1, wlo, acc2[1][nt], 0, 0, 0);
        }
    }

    float b2v[8];
#pragma unroll
    for (int nt = 0; nt < 8; ++nt) b2v[nt] = b2[nt * 16 + l15];

    float s[8], q[8];
#pragma unroll
    for (int nt = 0; nt < 8; ++nt) { s[nt] = 0.0f; q[nt] = 0.0f; }

#pragma unroll
    for (int m = 0; m < 2; ++m) {
#pragma unroll
        for (int rr = 0; rr < 4; ++rr) {
            int rg = row_base + m * 16 + l4 * 4 + rr;
            bool ok = rg < N_NODES;
#pragma unroll
            for (int nt = 0; nt < 8; ++nt) {
                float v = fmaxf(acc2[m][nt][rr] + b2v[nt], 0.0f);   // outer ReLU
                if (ok) {
                    h_raw[(size_t)rg * 128 + nt * 16 + l15] = v;
                    s[nt] += v;
                    q[nt] += v * v;
                }
            }
        }
    }
#pragma unroll
    for (int nt = 0; nt < 8; ++nt) {
        s[nt] += __shfl_xor(s[nt], 16); s[nt] += __shfl_xor(s[nt], 32);
        q[nt] += __shfl_xor(q[nt], 16); q[nt] += __shfl_xor(q[nt], 32);
    }
    if (l4 == 0) {
#pragma unroll
        for (int nt = 0; nt < 8; ++nt) {
            red_s[wave][nt * 16 + l15] = s[nt];
            red_q[wave][nt * 16 + l15] = q[nt];
        }
    }
    __syncthreads();
    if (t < 128) {
        part_s[blockIdx.x * 128 + t] = red_s[0][t] + red_s[1][t];
        part_q[blockIdx.x * 128 + t] = red_q[0][t] + red_q[1][t];
    }
}

// 256 blocks: block b reduces channel (b&127) of (b>>7 ? part_q : part_s)
__global__ __launch_bounds__(256) void bn_reduce(
        const float* __restrict__ part_s, const float* __restrict__ part_q,
        float* __restrict__ bn_sum, float* __restrict__ bn_sq, int nparts) {
    __shared__ float red[256];
    int c = blockIdx.x & 127;
    const float* src = (blockIdx.x >> 7) ? part_q : part_s;
    float* dst = (blockIdx.x >> 7) ? bn_sq : bn_sum;
    float a = 0.0f;
    for (int p = threadIdx.x; p < nparts; p += 256) a += src[p * 128 + c];
    red[threadIdx.x] = a;
    __syncthreads();
    for (int s = 128; s > 0; s >>= 1) {
        if (threadIdx.x < s) red[threadIdx.x] += red[threadIdx.x + s];
        __syncthreads();
    }
    if (threadIdx.x == 0) dst[c] = red[0];
}

// normalize in place (fp32); optionally duplicate to a second buffer
__global__ void bn_apply(float* __restrict__ h,
                         const float* __restrict__ bn_sum, const float* __restrict__ bn_sq,
                         const float* __restrict__ gamma, const float* __restrict__ beta,
                         float4* __restrict__ dup) {
    int i4 = blockIdx.x * 256 + threadIdx.x;
    if (i4 >= N_NODES * DIM / 4) return;
    float4 v = ((const float4*)h)[i4];
    int c0 = (i4 & 31) * 4;
    const float invN = 1.0f / (float)N_NODES;
    float* vp = (float*)&v;
#pragma unroll
    for (int j = 0; j < 4; ++j) {
        int c = c0 + j;
        float mean = bn_sum[c] * invN;
        float var = fmaxf(bn_sq[c] * invN - mean * mean, 0.0f);
        float inv = rsqrtf(var + BN_EPS);
        vp[j] = (vp[j] - mean) * inv * gamma[c] + beta[c];
    }
    ((float4*)h)[i4] = v;
    if (dup) dup[i4] = v;
}

// ---------------- launch ----------------

extern "C" void kernel_launch(void* const* d_in, const int* in_sizes, int n_in,
                              void* d_out, int out_size, void* d_ws, size_t ws_size,
                              hipStream_t stream) {
    const float* x     = (const float*)d_in[0];
    const int*   eidx  = (const int*)d_in[1];
    const float* W1    = (const float*)d_in[3];
    const float* b1    = (const float*)d_in[4];
    const float* W2    = (const float*)d_in[5];
    const float* b2    = (const float*)d_in[6];
    const float* gamma = (const float*)d_in[7];
    const float* beta  = (const float*)d_in[8];

    int n_edges = in_sizes[1] / 2;
    const int* src = eidx;
    const int* dst = eidx + n_edges;

    const int NBLK = (N_NODES + 63) / 64;    // 782 mlp blocks

    int* counts    = (int*)d_ws;                       // 50000
    int* offsets   = counts + N_NODES;                 // 50001
    int* cursor    = offsets + N_NODES + 1;            // 50000
    int* blocksums = cursor + N_NODES;                 // 256
    int* csr_src   = blocksums + 256;                  // n_edges
    float* part_s  = (float*)(csr_src + n_edges);      // NBLK*128
    float* part_q  = part_s + NBLK * 128;              // NBLK*128
    float* bn_sum  = part_q + NBLK * 128;              // 128
    float* bn_sq   = bn_sum + DIM;                     // 128
    size_t wp_off = (((size_t)(bn_sq + DIM) - (size_t)d_ws) + 15) & ~(size_t)15;
    unsigned short* wp = (unsigned short*)((char*)d_ws + wp_off);   // 5*2*32768 bf16 (hi+lo)

    float* out = (float*)d_out;
    // slot 0 doubles as bf16 hi/lo scratch until the last layer writes it
    unsigned int* h_hi_u = (unsigned int*)d_out;                    // [N][64] uints
    unsigned int* h_lo_u = h_hi_u + (size_t)N_NODES * 64;
    const unsigned short* h_hi = (const unsigned short*)h_hi_u;
    const unsigned short* h_lo = (const unsigned short*)h_lo_u;

    // CSR build
    hipMemsetAsync(counts, 0, N_NODES * sizeof(int), stream);
    hist_kernel<<<(n_edges + 255) / 256, 256, 0, stream>>>(dst, n_edges, counts);
    int nb = (N_NODES + 255) / 256;
    scan_local<<<nb, 256, 0, stream>>>(counts, N_NODES, offsets, blocksums);
    scan_block<<<1, 256, 0, stream>>>(blocksums, nb);
    scan_add<<<nb, 256, 0, stream>>>(offsets, cursor, blocksums, N_NODES, n_edges);
    scatter_kernel<<<(n_edges + 255) / 256, 256, 0, stream>>>(src, dst, n_edges, cursor, csr_src);

    wpack_prep<<<(N_LAYERS * 2 * 16384 + 255) / 256, 256, 0, stream>>>(W1, W2, wp);

    const float* layer_in = x;
    for (int i = 0; i < N_LAYERS; ++i) {
        float* layer_out = out + (size_t)(1 + i) * N_NODES * DIM;
        agg_kernel<<<(N_NODES + 3) / 4, 256, 0, stream>>>(layer_in, csr_src, offsets,
                                                          h_hi_u, h_lo_u);
        mlp_mfma<<<NBLK, 128, 0, stream>>>(
            h_hi, h_lo,
            (const short8*)(wp + (size_t)(i * 2) * 32768), b1 + (size_t)i * DIM,
            (const short8*)(wp + (size_t)(i * 2 + 1) * 32768), b2 + (size_t)i * DIM,
            layer_out, part_s, part_q);
        bn_reduce<<<256, 256, 0, stream>>>(part_s, part_q, bn_sum, bn_sq, NBLK);
        // last layer: also write the final-h slot (out[0:N*D]) directly
        bn_apply<<<(N_NODES * DIM / 4 + 255) / 256, 256, 0, stream>>>(
            layer_out, bn_sum, bn_sq, gamma + (size_t)i * DIM, beta + (size_t)i * DIM,
            (i == N_LAYERS - 1) ? (float4*)out : (float4*)nullptr);
        layer_in = layer_out;
    }
}

// Round 8
// 531.347 us; speedup vs baseline: 3.1294x; 1.1271x over previous
//
#include <hip/hip_runtime.h>

#define N_NODES 50000
#define DIM 128
#define N_LAYERS 5
#define BN_EPS 1e-5f

typedef __attribute__((ext_vector_type(8))) short short8;
typedef __attribute__((ext_vector_type(4))) float f32x4;

__device__ __forceinline__ float bf2f(unsigned int u16) {
    union { unsigned int i; float f; } c; c.i = u16 << 16; return c.f;
}
__device__ __forceinline__ unsigned short f2bf(float f) {
    union { float f; unsigned int i; } c; c.f = f;
    unsigned int v = c.i + 0x7FFFu + ((c.i >> 16) & 1u);   // RNE
    return (unsigned short)(v >> 16);
}

// ---------------- CSR build ----------------

__global__ void hist_kernel(const int* __restrict__ dst, int n_edges, int* __restrict__ counts) {
    int e = blockIdx.x * 256 + threadIdx.x;
    if (e < n_edges) atomicAdd(&counts[dst[e]], 1);
}

__global__ void scan_local(const int* __restrict__ counts, int n,
                           int* __restrict__ offsets, int* __restrict__ blocksums) {
    __shared__ int temp[256];
    int t = threadIdx.x;
    int i = blockIdx.x * 256 + t;
    int v = (i < n) ? counts[i] : 0;
    temp[t] = v;
    __syncthreads();
    for (int off = 1; off < 256; off <<= 1) {
        int add = (t >= off) ? temp[t - off] : 0;
        __syncthreads();
        temp[t] += add;
        __syncthreads();
    }
    if (i < n) offsets[i] = temp[t] - v;
    if (t == 255) blocksums[blockIdx.x] = temp[255];
}

__global__ void scan_block(int* __restrict__ blocksums, int nb) {
    __shared__ int temp[256];
    int t = threadIdx.x;
    int v = (t < nb) ? blocksums[t] : 0;
    temp[t] = v;
    __syncthreads();
    for (int off = 1; off < 256; off <<= 1) {
        int add = (t >= off) ? temp[t - off] : 0;
        __syncthreads();
        temp[t] += add;
        __syncthreads();
    }
    if (t < nb) blocksums[t] = temp[t] - v;
}

__global__ void scan_add(int* __restrict__ offsets, int* __restrict__ cursor,
                         const int* __restrict__ blocksums, int n, int n_edges) {
    int i = blockIdx.x * 256 + threadIdx.x;
    if (i < n) {
        int val = offsets[i] + blocksums[blockIdx.x];
        offsets[i] = val;
        cursor[i] = val;
    }
    if (i == 0) offsets[n] = n_edges;
}

__global__ void scatter_kernel(const int* __restrict__ src, const int* __restrict__ dst,
                               int n_edges, int* __restrict__ cursor, int* __restrict__ csr_src) {
    int e = blockIdx.x * 256 + threadIdx.x;
    if (e < n_edges) {
        int p = atomicAdd(&cursor[dst[e]], 1);
        csr_src[p] = src[e];
    }
}

// ---------------- prep ----------------

// pack W1/W2 (all layers) into MFMA B-fragment order, hi+lo bf16 planes.
__global__ void wpack_prep(const float* __restrict__ W1, const float* __restrict__ W2,
                           unsigned short* __restrict__ wp) {
    int idx = blockIdx.x * 256 + threadIdx.x;
    if (idx >= N_LAYERS * 2 * 16384) return;
    int j    = idx & 7;
    int lane = (idx >> 3) & 63;
    int nt   = (idx >> 9) & 7;
    int ks   = (idx >> 12) & 3;
    int mat  = (idx >> 14) & 1;
    int lay  = idx >> 15;
    int l15 = lane & 15, l4 = lane >> 4;
    int col = nt * 16 + l15;
    int kp = ks * 32 + l4 * 8 + j;
    int k = mat ? ((kp & 7) * 16 + (kp >> 3)) : kp;
    const float* W = mat ? W2 : W1;
    float w = W[((size_t)lay * 128 + k) * 128 + col];
    unsigned short hi = f2bf(w);
    unsigned short lo = f2bf(w - bf2f(hi));
    size_t base = (size_t)(lay * 2 + mat) * 32768;
    size_t inner = (size_t)((ks * 8 + nt) * 64 + lane) * 8 + j;
    wp[base + inner] = hi;
    wp[base + 16384 + inner] = lo;
}

// ---------------- per-layer kernels ----------------

// layer-0 aggregation: fp32 float4 gathers, 2 edges/instr, depth-8 pipeline.
__global__ void agg_kernel(const float* __restrict__ x, const int* __restrict__ csr_src,
                           const int* __restrict__ offsets,
                           unsigned int* __restrict__ h_hi_u, unsigned int* __restrict__ h_lo_u) {
    int wave = threadIdx.x >> 6;
    int l = threadIdx.x & 63;
    int node = blockIdx.x * 4 + wave;
    if (node >= N_NODES) return;
    int half = l >> 5;
    int d4 = l & 31;
    int beg = offsets[node], end = offsets[node + 1];
    const float4* x4 = (const float4*)x;

    float4 acc = make_float4(0.f, 0.f, 0.f, 0.f);
    if (half == 0) acc = x4[(size_t)node * 32 + d4];

    for (int e = beg; e < end; e += 16) {
        int s[8];
#pragma unroll
        for (int i = 0; i < 8; ++i) s[i] = csr_src[min(e + 2 * i + half, end - 1)];
        float4 v[8];
#pragma unroll
        for (int i = 0; i < 8; ++i) v[i] = x4[(size_t)s[i] * 32 + d4];
#pragma unroll
        for (int i = 0; i < 8; ++i) {
            float w = (e + 2 * i + half < end) ? 1.0f : 0.0f;
            acc.x = fmaf(v[i].x, w, acc.x);
            acc.y = fmaf(v[i].y, w, acc.y);
            acc.z = fmaf(v[i].z, w, acc.z);
            acc.w = fmaf(v[i].w, w, acc.w);
        }
    }

    acc.x += __shfl_xor(acc.x, 32);
    acc.y += __shfl_xor(acc.y, 32);
    acc.z += __shfl_xor(acc.z, 32);
    acc.w += __shfl_xor(acc.w, 32);

    unsigned short h0 = f2bf(acc.x), h1 = f2bf(acc.y);
    unsigned short h2 = f2bf(acc.z), h3 = f2bf(acc.w);
    if (half == 0) {
        uint2 hv;
        hv.x = (unsigned int)h0 | ((unsigned int)h1 << 16);
        hv.y = (unsigned int)h2 | ((unsigned int)h3 << 16);
        ((uint2*)h_hi_u)[(size_t)node * 32 + d4] = hv;
    } else {
        unsigned short l0 = f2bf(acc.x - bf2f(h0)), l1 = f2bf(acc.y - bf2f(h1));
        unsigned short l2 = f2bf(acc.z - bf2f(h2)), l3 = f2bf(acc.w - bf2f(h3));
        uint2 lv;
        lv.x = (unsigned int)l0 | ((unsigned int)l1 << 16);
        lv.y = (unsigned int)l2 | ((unsigned int)l3 << 16);
        ((uint2*)h_lo_u)[(size_t)node * 32 + d4] = lv;
    }
}

// layers 1..4: bf16 gathers (256 B/row, uint2/lane), 2 edges/instr, depth-8.
__global__ void agg_bf_kernel(const uint2* __restrict__ xbf2, const int* __restrict__ csr_src,
                              const int* __restrict__ offsets,
                              unsigned int* __restrict__ h_hi_u, unsigned int* __restrict__ h_lo_u) {
    int wave = threadIdx.x >> 6;
    int l = threadIdx.x & 63;
    int node = blockIdx.x * 4 + wave;
    if (node >= N_NODES) return;
    int half = l >> 5;
    int d = l & 31;          // uint2 chunk (4 bf16 cols) of the 128-dim row
    int beg = offsets[node], end = offsets[node + 1];

    float a0 = 0.f, a1 = 0.f, a2 = 0.f, a3 = 0.f;
    if (half == 0) {
        uint2 u = xbf2[(size_t)node * 32 + d];   // self term
        a0 = bf2f(u.x & 0xFFFFu); a1 = bf2f(u.x >> 16);
        a2 = bf2f(u.y & 0xFFFFu); a3 = bf2f(u.y >> 16);
    }

    for (int e = beg; e < end; e += 16) {
        int s[8];
#pragma unroll
        for (int i = 0; i < 8; ++i) s[i] = csr_src[min(e + 2 * i + half, end - 1)];
        uint2 v[8];
#pragma unroll
        for (int i = 0; i < 8; ++i) v[i] = xbf2[(size_t)s[i] * 32 + d];
#pragma unroll
        for (int i = 0; i < 8; ++i) {
            float w = (e + 2 * i + half < end) ? 1.0f : 0.0f;
            a0 = fmaf(bf2f(v[i].x & 0xFFFFu), w, a0);
            a1 = fmaf(bf2f(v[i].x >> 16),     w, a1);
            a2 = fmaf(bf2f(v[i].y & 0xFFFFu), w, a2);
            a3 = fmaf(bf2f(v[i].y >> 16),     w, a3);
        }
    }

    a0 += __shfl_xor(a0, 32);
    a1 += __shfl_xor(a1, 32);
    a2 += __shfl_xor(a2, 32);
    a3 += __shfl_xor(a3, 32);

    unsigned short h0 = f2bf(a0), h1 = f2bf(a1), h2 = f2bf(a2), h3 = f2bf(a3);
    if (half == 0) {
        uint2 hv;
        hv.x = (unsigned int)h0 | ((unsigned int)h1 << 16);
        hv.y = (unsigned int)h2 | ((unsigned int)h3 << 16);
        ((uint2*)h_hi_u)[(size_t)node * 32 + d] = hv;
    } else {
        unsigned short l0 = f2bf(a0 - bf2f(h0)), l1 = f2bf(a1 - bf2f(h1));
        unsigned short l2 = f2bf(a2 - bf2f(h2)), l3 = f2bf(a3 - bf2f(h3));
        uint2 lv;
        lv.x = (unsigned int)l0 | ((unsigned int)l1 << 16);
        lv.y = (unsigned int)l2 | ((unsigned int)l3 << 16);
        ((uint2*)h_lo_u)[(size_t)node * 32 + d] = lv;
    }
}

// fused MFMA MLP (bf16x2 split, 3-product): ReLU(h@W1+b1)@W2+b2 -> ReLU
// -> h_raw (fp32) + per-block BN partials
__global__ __launch_bounds__(128) void mlp_mfma(
        const unsigned short* __restrict__ h_hi, const unsigned short* __restrict__ h_lo,
        const short8* __restrict__ wp1, const float* __restrict__ b1,
        const short8* __restrict__ wp2, const float* __restrict__ b2,
        float* __restrict__ h_raw,
        float* __restrict__ part_s, float* __restrict__ part_q) {
    __shared__ unsigned short mid_hi[2][2][16][128];   // [wave][m][row][kp], XOR-swizzled
    __shared__ unsigned short mid_lo[2][2][16][128];
    __shared__ float red_s[2][128], red_q[2][128];
    int t = threadIdx.x, wave = t >> 6, l = t & 63;
    int l15 = l & 15, l4 = l >> 4;
    int row_base = blockIdx.x * 64 + wave * 32;

    int r0 = row_base + l15, r1 = r0 + 16;
    int cr0 = min(r0, N_NODES - 1), cr1 = min(r1, N_NODES - 1);
    const short8* ah0p = (const short8*)(h_hi + (size_t)cr0 * 128);
    const short8* ah1p = (const short8*)(h_hi + (size_t)cr1 * 128);
    const short8* al0p = (const short8*)(h_lo + (size_t)cr0 * 128);
    const short8* al1p = (const short8*)(h_lo + (size_t)cr1 * 128);

    const short8* wp1l = wp1 + 2048;   // lo plane
    const short8* wp2l = wp2 + 2048;

    f32x4 acc[2][8];
#pragma unroll
    for (int m = 0; m < 2; ++m)
#pragma unroll
        for (int nt = 0; nt < 8; ++nt) acc[m][nt] = (f32x4)0.0f;

#pragma unroll
    for (int ks = 0; ks < 4; ++ks) {
        short8 ah0 = ah0p[ks * 4 + l4];
        short8 ah1 = ah1p[ks * 4 + l4];
        short8 al0 = al0p[ks * 4 + l4];
        short8 al1 = al1p[ks * 4 + l4];
#pragma unroll
        for (int nt = 0; nt < 8; ++nt) {
            short8 whi = wp1[(ks * 8 + nt) * 64 + l];
            short8 wlo = wp1l[(ks * 8 + nt) * 64 + l];
            acc[0][nt] = __builtin_amdgcn_mfma_f32_16x16x32_bf16(ah0, whi, acc[0][nt], 0, 0, 0);
            acc[0][nt] = __builtin_amdgcn_mfma_f32_16x16x32_bf16(al0, whi, acc[0][nt], 0, 0, 0);
            acc[0][nt] = __builtin_amdgcn_mfma_f32_16x16x32_bf16(ah0, wlo, acc[0][nt], 0, 0, 0);
            acc[1][nt] = __builtin_amdgcn_mfma_f32_16x16x32_bf16(ah1, whi, acc[1][nt], 0, 0, 0);
            acc[1][nt] = __builtin_amdgcn_mfma_f32_16x16x32_bf16(al1, whi, acc[1][nt], 0, 0, 0);
            acc[1][nt] = __builtin_amdgcn_mfma_f32_16x16x32_bf16(ah1, wlo, acc[1][nt], 0, 0, 0);
        }
    }

    float b1v[8];
#pragma unroll
    for (int nt = 0; nt < 8; ++nt) b1v[nt] = b1[nt * 16 + l15];

#pragma unroll
    for (int m = 0; m < 2; ++m) {
#pragma unroll
        for (int rr = 0; rr < 4; ++rr) {
            int row = l4 * 4 + rr;
            short8 ph, pl;
#pragma unroll
            for (int nt = 0; nt < 8; ++nt) {
                float v = fmaxf(acc[m][nt][rr] + b1v[nt], 0.0f);
                unsigned short hv = f2bf(v);
                ph[nt] = (short)hv;
                pl[nt] = (short)f2bf(v - bf2f(hv));
            }
            int off = (l15 * 16) ^ ((row & 7) << 4);
            *(short8*)((char*)&mid_hi[wave][m][row][0] + off) = ph;
            *(short8*)((char*)&mid_lo[wave][m][row][0] + off) = pl;
        }
    }
    __syncthreads();

    f32x4 acc2[2][8];
#pragma unroll
    for (int m = 0; m < 2; ++m)
#pragma unroll
        for (int nt = 0; nt < 8; ++nt) acc2[m][nt] = (f32x4)0.0f;

#pragma unroll
    for (int ks = 0; ks < 4; ++ks) {
        int off = (ks * 64 + l4 * 16) ^ ((l15 & 7) << 4);
        short8 ah0 = *(const short8*)((char*)&mid_hi[wave][0][l15][0] + off);
        short8 ah1 = *(const short8*)((char*)&mid_hi[wave][1][l15][0] + off);
        short8 al0 = *(const short8*)((char*)&mid_lo[wave][0][l15][0] + off);
        short8 al1 = *(const short8*)((char*)&mid_lo[wave][1][l15][0] + off);
#pragma unroll
        for (int nt = 0; nt < 8; ++nt) {
            short8 whi = wp2[(ks * 8 + nt) * 64 + l];
            short8 wlo = wp2l[(ks * 8 + nt) * 64 + l];
            acc2[0][nt] = __builtin_amdgcn_mfma_f32_16x16x32_bf16(ah0, whi, acc2[0][nt], 0, 0, 0);
            acc2[0][nt] = __builtin_amdgcn_mfma_f32_16x16x32_bf16(al0, whi, acc2[0][nt], 0, 0, 0);
            acc2[0][nt] = __builtin_amdgcn_mfma_f32_16x16x32_bf16(ah0, wlo, acc2[0][nt], 0, 0, 0);
            acc2[1][nt] = __builtin_amdgcn_mfma_f32_16x16x32_bf16(ah1, whi, acc2[1][nt], 0, 0, 0);
            acc2[1][nt] = __builtin_amdgcn_mfma_f32_16x16x32_bf16(al1, whi, acc2[1][nt], 0, 0, 0);
            acc2[1][nt] = __builtin_amdgcn_mfma_f32_16x16x32_bf16(ah1, wlo, acc2[1][nt], 0, 0, 0);
        }
    }

    float b2v[8];
#pragma unroll
    for (int nt = 0; nt < 8; ++nt) b2v[nt] = b2[nt * 16 + l15];

    float s[8], q[8];
#pragma unroll
    for (int nt = 0; nt < 8; ++nt) { s[nt] = 0.0f; q[nt] = 0.0f; }

#pragma unroll
    for (int m = 0; m < 2; ++m) {
#pragma unroll
        for (int rr = 0; rr < 4; ++rr) {
            int rg = row_base + m * 16 + l4 * 4 + rr;
            bool ok = rg < N_NODES;
#pragma unroll
            for (int nt = 0; nt < 8; ++nt) {
                float v = fmaxf(acc2[m][nt][rr] + b2v[nt], 0.0f);   // outer ReLU
                if (ok) {
                    h_raw[(size_t)rg * 128 + nt * 16 + l15] = v;
                    s[nt] += v;
                    q[nt] += v * v;
                }
            }
        }
    }
#pragma unroll
    for (int nt = 0; nt < 8; ++nt) {
        s[nt] += __shfl_xor(s[nt], 16); s[nt] += __shfl_xor(s[nt], 32);
        q[nt] += __shfl_xor(q[nt], 16); q[nt] += __shfl_xor(q[nt], 32);
    }
    if (l4 == 0) {
#pragma unroll
        for (int nt = 0; nt < 8; ++nt) {
            red_s[wave][nt * 16 + l15] = s[nt];
            red_q[wave][nt * 16 + l15] = q[nt];
        }
    }
    __syncthreads();
    if (t < 128) {
        part_s[blockIdx.x * 128 + t] = red_s[0][t] + red_s[1][t];
        part_q[blockIdx.x * 128 + t] = red_q[0][t] + red_q[1][t];
    }
}

// 256 blocks: block b reduces channel (b&127) of (b>>7 ? part_q : part_s)
__global__ __launch_bounds__(256) void bn_reduce(
        const float* __restrict__ part_s, const float* __restrict__ part_q,
        float* __restrict__ bn_sum, float* __restrict__ bn_sq, int nparts) {
    __shared__ float red[256];
    int c = blockIdx.x & 127;
    const float* src = (blockIdx.x >> 7) ? part_q : part_s;
    float* dst = (blockIdx.x >> 7) ? bn_sq : bn_sum;
    float a = 0.0f;
    for (int p = threadIdx.x; p < nparts; p += 256) a += src[p * 128 + c];
    red[threadIdx.x] = a;
    __syncthreads();
    for (int s = 128; s > 0; s >>= 1) {
        if (threadIdx.x < s) red[threadIdx.x] += red[threadIdx.x + s];
        __syncthreads();
    }
    if (threadIdx.x == 0) dst[c] = red[0];
}

// normalize in place (fp32); optionally emit bf16 next-layer input and/or fp32 dup
__global__ void bn_apply(float* __restrict__ h,
                         const float* __restrict__ bn_sum, const float* __restrict__ bn_sq,
                         const float* __restrict__ gamma, const float* __restrict__ beta,
                         uint2* __restrict__ xbf_next, float4* __restrict__ dup) {
    int i4 = blockIdx.x * 256 + threadIdx.x;
    if (i4 >= N_NODES * DIM / 4) return;
    float4 v = ((const float4*)h)[i4];
    int c0 = (i4 & 31) * 4;
    const float invN = 1.0f / (float)N_NODES;
    float* vp = (float*)&v;
#pragma unroll
    for (int j = 0; j < 4; ++j) {
        int c = c0 + j;
        float mean = bn_sum[c] * invN;
        float var = fmaxf(bn_sq[c] * invN - mean * mean, 0.0f);
        float inv = rsqrtf(var + BN_EPS);
        vp[j] = (vp[j] - mean) * inv * gamma[c] + beta[c];
    }
    ((float4*)h)[i4] = v;
    if (xbf_next) {
        unsigned int lo = (unsigned int)f2bf(vp[0]) | ((unsigned int)f2bf(vp[1]) << 16);
        unsigned int hi = (unsigned int)f2bf(vp[2]) | ((unsigned int)f2bf(vp[3]) << 16);
        xbf_next[i4] = make_uint2(lo, hi);
    }
    if (dup) dup[i4] = v;
}

// ---------------- launch ----------------

extern "C" void kernel_launch(void* const* d_in, const int* in_sizes, int n_in,
                              void* d_out, int out_size, void* d_ws, size_t ws_size,
                              hipStream_t stream) {
    const float* x     = (const float*)d_in[0];
    const int*   eidx  = (const int*)d_in[1];
    const float* W1    = (const float*)d_in[3];
    const float* b1    = (const float*)d_in[4];
    const float* W2    = (const float*)d_in[5];
    const float* b2    = (const float*)d_in[6];
    const float* gamma = (const float*)d_in[7];
    const float* beta  = (const float*)d_in[8];

    int n_edges = in_sizes[1] / 2;
    const int* src = eidx;
    const int* dst = eidx + n_edges;

    const int NBLK = (N_NODES + 63) / 64;    // 782 mlp blocks

    int* counts    = (int*)d_ws;                       // 50000
    int* offsets   = counts + N_NODES;                 // 50001
    int* cursor    = offsets + N_NODES + 1;            // 50000
    int* blocksums = cursor + N_NODES;                 // 256
    int* csr_src   = blocksums + 256;                  // n_edges
    float* part_s  = (float*)(csr_src + n_edges);      // NBLK*128
    float* part_q  = part_s + NBLK * 128;              // NBLK*128
    float* bn_sum  = part_q + NBLK * 128;              // 128
    float* bn_sq   = bn_sum + DIM;                     // 128
    size_t wp_off = (((size_t)(bn_sq + DIM) - (size_t)d_ws) + 15) & ~(size_t)15;
    unsigned short* wp = (unsigned short*)((char*)d_ws + wp_off);   // 5*2*32768 bf16 (hi+lo)
    // bf16 next-layer input (written by bn_apply for layers 0..3)
    uint2* x_bf2 = (uint2*)(wp + (size_t)N_LAYERS * 2 * 32768);     // [N][32] uint2 = 12.8 MB

    float* out = (float*)d_out;
    // slot 0 doubles as bf16 hi/lo scratch until the last layer writes it
    unsigned int* h_hi_u = (unsigned int*)d_out;                    // [N][64] uints
    unsigned int* h_lo_u = h_hi_u + (size_t)N_NODES * 64;
    const unsigned short* h_hi = (const unsigned short*)h_hi_u;
    const unsigned short* h_lo = (const unsigned short*)h_lo_u;

    // CSR build
    hipMemsetAsync(counts, 0, N_NODES * sizeof(int), stream);
    hist_kernel<<<(n_edges + 255) / 256, 256, 0, stream>>>(dst, n_edges, counts);
    int nb = (N_NODES + 255) / 256;
    scan_local<<<nb, 256, 0, stream>>>(counts, N_NODES, offsets, blocksums);
    scan_block<<<1, 256, 0, stream>>>(blocksums, nb);
    scan_add<<<nb, 256, 0, stream>>>(offsets, cursor, blocksums, N_NODES, n_edges);
    scatter_kernel<<<(n_edges + 255) / 256, 256, 0, stream>>>(src, dst, n_edges, cursor, csr_src);

    wpack_prep<<<(N_LAYERS * 2 * 16384 + 255) / 256, 256, 0, stream>>>(W1, W2, wp);

    for (int i = 0; i < N_LAYERS; ++i) {
        float* layer_out = out + (size_t)(1 + i) * N_NODES * DIM;
        if (i == 0)
            agg_kernel<<<(N_NODES + 3) / 4, 256, 0, stream>>>(x, csr_src, offsets,
                                                              h_hi_u, h_lo_u);
        else
            agg_bf_kernel<<<(N_NODES + 3) / 4, 256, 0, stream>>>(x_bf2, csr_src, offsets,
                                                                 h_hi_u, h_lo_u);
        mlp_mfma<<<NBLK, 128, 0, stream>>>(
            h_hi, h_lo,
            (const short8*)(wp + (size_t)(i * 2) * 32768), b1 + (size_t)i * DIM,
            (const short8*)(wp + (size_t)(i * 2 + 1) * 32768), b2 + (size_t)i * DIM,
            layer_out, part_s, part_q);
        bn_reduce<<<256, 256, 0, stream>>>(part_s, part_q, bn_sum, bn_sq, NBLK);
        bn_apply<<<(N_NODES * DIM / 4 + 255) / 256, 256, 0, stream>>>(
            layer_out, bn_sum, bn_sq, gamma + (size_t)i * DIM, beta + (size_t)i * DIM,
            (i < N_LAYERS - 1) ? x_bf2 : (uint2*)nullptr,
            (i == N_LAYERS - 1) ? (float4*)out : (float4*)nullptr);
    }
}